// Round 1
// baseline (627.305 us; speedup 1.0000x reference)
//
#include <hip/hip_runtime.h>
#include <math.h>

#define BATCH   128
#define NFREQ   96000      // input row length (freq pts); irfft length
#define M_HALF  48000      // complex IDFT length
#define NFRAMES 374
#define NBINS   257

#define PI_D 3.14159265358979323846

__device__ __forceinline__ float2 cmulf(float2 a, float2 b) {
  return make_float2(a.x * b.x - a.y * b.y, a.x * b.y + a.y * b.x);
}

// ---------------------------------------------------------------- tables
__global__ void setup_kernel(float2* __restrict__ Wm, float2* __restrict__ Wpack,
                             float2* __restrict__ W512, float* __restrict__ hann) {
  int i = blockIdx.x * blockDim.x + threadIdx.x;
  if (i < M_HALF) {
    double th = 2.0 * PI_D * (double)i / (double)M_HALF;   // exp(+i th): inverse FFT
    double s, c; sincos(th, &s, &c);
    Wm[i] = make_float2((float)c, (float)s);
    double th2 = PI_D * (double)i / (double)M_HALF;        // 2*pi*i/96000
    double s2, c2; sincos(th2, &s2, &c2);
    Wpack[i] = make_float2((float)c2, (float)s2);
  }
  if (i < 512) {
    double th = -2.0 * PI_D * (double)i / 512.0;           // forward FFT
    double s, c; sincos(th, &s, &c);
    W512[i] = make_float2((float)c, (float)s);
    hann[i] = (float)(0.5 * (1.0 - cos(2.0 * PI_D * (double)i / 512.0)));
  }
}

// ------------------------------------------------- pack: X (half spec) -> Zf
// rows [0,c): target batch b0+row ; rows [c,2c): ach batch b0+row-c
__global__ __launch_bounds__(256) void pack_kernel(
    const float* __restrict__ tre, const float* __restrict__ tim,
    const float* __restrict__ are, const float* __restrict__ aim,
    float2* __restrict__ A, const float2* __restrict__ Wpack, int b0, int c) {
  int idx = blockIdx.x * blockDim.x + threadIdx.x;
  int total = 2 * c * M_HALF;
  if (idx >= total) return;
  int row = idx / M_HALF;
  int k = idx - row * M_HALF;
  int isA = row >= c;
  int b = b0 + (isA ? row - c : row);
  const float* re = isA ? are : tre;
  const float* im = isA ? aim : tim;
  const float* rr = re + (size_t)b * NFREQ;
  const float* ii = im + (size_t)b * NFREQ;
  float xr = rr[k];
  float xi = (k == 0) ? 0.f : ii[k];          // c2r drops Im at DC
  int mk = M_HALF - k;                         // in (0, M]
  float yr = rr[mk];
  float yi = (mk == M_HALF) ? 0.f : ii[mk];    // c2r drops Im at Nyquist
  // conj(X[M-k]) = (yr, -yi)
  float Er = 0.5f * (xr + yr);
  float Ei = 0.5f * (xi - yi);
  float Dr = 0.5f * (xr - yr);
  float Di = 0.5f * (xi + yi);
  float2 wp = Wpack[k];
  float tr = wp.x * Dr - wp.y * Di;
  float ti = wp.x * Di + wp.y * Dr;
  // Zf = E + i*(wp*D), scaled by 1/M
  const float sc = 1.0f / (float)M_HALF;
  A[(size_t)row * M_HALF + k] = make_float2((Er - ti) * sc, (Ei + tr) * sc);
}

// --------------------------------------- mixed-radix Stockham IDFT stage (DIF)
// x[q + S*(p + MM*j)] -> y[q + S*(R*p + u)] = (sum_j x_j w_R^{uj}) * w_NN^{up}
template <int R, int S, int NN>
__global__ __launch_bounds__(256) void stage_kernel(
    const float2* __restrict__ x, float2* __restrict__ y,
    const float2* __restrict__ Wm, int rows) {
  constexpr int MM = NN / R;
  constexpr int ITEMS = M_HALF / R;   // = MM * S
  int idx = blockIdx.x * blockDim.x + threadIdx.x;
  if (idx >= rows * ITEMS) return;
  int row = idx / ITEMS;
  int t = idx - row * ITEMS;
  int q = t % S;
  int p = t / S;
  const float2* xr = x + (size_t)row * M_HALF;
  float2* yr = y + (size_t)row * M_HALF;
  float2 a[R];
#pragma unroll
  for (int j = 0; j < R; ++j) a[j] = xr[q + S * (p + MM * j)];
  float2 wr[R];
#pragma unroll
  for (int t2 = 0; t2 < R; ++t2) wr[t2] = Wm[t2 * (M_HALF / R)];
  float2 twb = Wm[(size_t)p * (M_HALF / NN)];
  float2 tw = make_float2(1.f, 0.f);
#pragma unroll
  for (int u = 0; u < R; ++u) {
    float2 acc = a[0];
#pragma unroll
    for (int j = 1; j < R; ++j) {
      float2 w = wr[(u * j) % R];
      acc.x += a[j].x * w.x - a[j].y * w.y;
      acc.y += a[j].x * w.y + a[j].y * w.x;
    }
    acc = cmulf(acc, tw);
    yr[q + S * (R * p + u)] = acc;
    tw = cmulf(tw, twb);
  }
}

// ------------------------------------------------- STFT frame -> power bins
__global__ __launch_bounds__(128) void stft_kernel(
    const float* __restrict__ xtime, float* __restrict__ P,
    const float2* __restrict__ W512, const float* __restrict__ hann) {
  __shared__ float2 U[512];
  __shared__ float2 V[512];
  const int frame = blockIdx.x;
  const int row = blockIdx.y;
  const int tid = threadIdx.x;
  const float* xr = xtime + (size_t)row * NFREQ + (size_t)frame * 256;
#pragma unroll
  for (int j = tid; j < 512; j += 128)
    U[j] = make_float2(xr[j] * hann[j], 0.f);
  __syncthreads();
  float2* src = U;
  float2* dst = V;
  int logs = 0;
  for (int st = 0; st < 9; ++st) {
    int s = 1 << logs;
#pragma unroll
    for (int i = tid; i < 256; i += 128) {
      int q = i & (s - 1);
      int p = i >> logs;
      float2 a = src[q + s * p];
      float2 b = src[q + s * (p + (256 >> logs))];   // m = n/2 = 512/(2^{st+1}) = 256/s
      float2 sum = make_float2(a.x + b.x, a.y + b.y);
      float2 dif = make_float2(a.x - b.x, a.y - b.y);
      float2 w = W512[p << st];                       // w_n^{-p}, 512/n = 2^st
      float2 o1 = make_float2(dif.x * w.x - dif.y * w.y, dif.x * w.y + dif.y * w.x);
      dst[q + s * (2 * p)] = sum;
      dst[q + s * (2 * p + 1)] = o1;
    }
    __syncthreads();
    float2* tmp = src; src = dst; dst = tmp;
    logs++;
  }
  for (int bin = tid; bin < NBINS; bin += 128) {
    float2 v = src[bin];
    P[((size_t)row * NFRAMES + frame) * NBINS + bin] = v.x * v.x + v.y * v.y;
  }
}

// ------------------------------------- EDR reverse-cumsum + dB + L1 reduction
__global__ __launch_bounds__(320) void edr_kernel(const float* __restrict__ P,
                                                  double* accum, int c) {
  const int b = blockIdx.x;   // [0, c)
  const int tid = threadIdx.x;
  const float* Pt = P + (size_t)b * (NFRAMES * NBINS);
  const float* Pa = P + (size_t)(b + c) * (NFRAMES * NBINS);
  float sn = 0.f, sd = 0.f;
  if (tid < NBINS) {
    float ct = 0.f, ca = 0.f;
    for (int m = NFRAMES - 1; m >= 0; --m) {
      ct += Pt[m * NBINS + tid];
      ca += Pa[m * NBINS + tid];
      float lt = 10.f * log10f(ct);
      float la = 10.f * log10f(ca);
      sn += fabsf(lt - la);
      sd += fabsf(lt);
    }
  }
#pragma unroll
  for (int off = 32; off > 0; off >>= 1) {
    sn += __shfl_down(sn, off, 64);
    sd += __shfl_down(sd, off, 64);
  }
  __shared__ float wsn[5], wsd[5];
  int wave = tid >> 6;
  if ((tid & 63) == 0) { wsn[wave] = sn; wsd[wave] = sd; }
  __syncthreads();
  if (tid == 0) {
    float tn = 0.f, td = 0.f;
#pragma unroll
    for (int w = 0; w < 5; ++w) { tn += wsn[w]; td += wsd[w]; }
    atomicAdd(&accum[0], (double)tn);
    atomicAdd(&accum[1], (double)td);
  }
}

__global__ void final_kernel(const double* __restrict__ accum, float* __restrict__ out) {
  out[0] = (float)(accum[0] / accum[1]);
}

// ---------------------------------------------------------------- launcher
extern "C" void kernel_launch(void* const* d_in, const int* in_sizes, int n_in,
                              void* d_out, int out_size, void* d_ws, size_t ws_size,
                              hipStream_t stream) {
  const float* tre = (const float*)d_in[0];
  const float* tim = (const float*)d_in[1];
  const float* are = (const float*)d_in[2];
  const float* aim = (const float*)d_in[3];
  float* out = (float*)d_out;

  char* base = (char*)d_ws;
  size_t off = 0;
  auto take = [&](size_t bytes) -> char* {
    char* p = base + off;
    off += (bytes + 255) & ~(size_t)255;
    return p;
  };
  float2* Wm    = (float2*)take((size_t)M_HALF * sizeof(float2));
  float2* Wpack = (float2*)take((size_t)M_HALF * sizeof(float2));
  float2* W512  = (float2*)take(512 * sizeof(float2));
  float*  hann  = (float*)take(512 * sizeof(float));
  double* accum = (double*)take(2 * sizeof(double));
  size_t fixed = off;

  // choose batch-chunk size c so workspace fits
  const size_t perA = (size_t)768000;                 // 2*48000*8 per batch unit
  const size_t perP = (size_t)768944;                 // max(B ping buf, P buf) per unit
  int c = 1;
  const int cands[8] = {128, 64, 32, 16, 8, 4, 2, 1};
  for (int ci = 0; ci < 8; ++ci) {
    size_t need = fixed + ((cands[ci] * perA + 255) & ~(size_t)255)
                        + ((cands[ci] * perP + 255) & ~(size_t)255);
    if (need <= ws_size) { c = cands[ci]; break; }
  }
  float2* A = (float2*)take((size_t)c * perA);
  char* BP  = take((size_t)c * perP);
  float2* Bb = (float2*)BP;  // FFT ping-pong partner
  float*  P  = (float*)BP;   // power spectra (aliases Bb; Bb dead by then)

  setup_kernel<<<(M_HALF + 255) / 256, 256, 0, stream>>>(Wm, Wpack, W512, hann);
  hipMemsetAsync(accum, 0, 2 * sizeof(double), stream);

  for (int b0 = 0; b0 < BATCH; b0 += c) {
    int rows = 2 * c;
    int tot = rows * M_HALF;
    pack_kernel<<<(tot + 255) / 256, 256, 0, stream>>>(tre, tim, are, aim, A, Wpack, b0, c);
    // 48000 = 15 * 16 * 10 * 20 ; Stockham ping-pong A->B->A->B->A
    {
      int items = rows * (M_HALF / 15);
      stage_kernel<15, 1, 48000><<<(items + 255) / 256, 256, 0, stream>>>(A, Bb, Wm, rows);
    }
    {
      int items = rows * (M_HALF / 16);
      stage_kernel<16, 15, 3200><<<(items + 255) / 256, 256, 0, stream>>>(Bb, A, Wm, rows);
    }
    {
      int items = rows * (M_HALF / 10);
      stage_kernel<10, 240, 200><<<(items + 255) / 256, 256, 0, stream>>>(A, Bb, Wm, rows);
    }
    {
      int items = rows * (M_HALF / 20);
      stage_kernel<20, 2400, 20><<<(items + 255) / 256, 256, 0, stream>>>(Bb, A, Wm, rows);
    }
    // A (interleaved re/im of z[t]) IS the real time signal x[t] of length 96000
    stft_kernel<<<dim3(NFRAMES, rows), 128, 0, stream>>>((const float*)A, P, W512, hann);
    edr_kernel<<<c, 320, 0, stream>>>(P, accum, c);
  }
  final_kernel<<<1, 1, 0, stream>>>(accum, out);
}

// Round 2
// 488.484 us; speedup vs baseline: 1.2842x; 1.2842x over previous
//
#include <hip/hip_runtime.h>
#include <math.h>

#define BATCH   128
#define NFREQ   96000      // input row length (freq pts); irfft length
#define M_HALF  48000      // complex IDFT length
#define NFRAMES 374
#define NBINS   257
#define NG      11         // frame groups for segmented reverse cumsum
#define GLEN    34         // 11 * 34 = 374 exactly
#define FPW     4          // frames per wave in stft kernel

#define PI_D 3.14159265358979323846

__device__ __forceinline__ float2 cmulf(float2 a, float2 b) {
  return make_float2(a.x * b.x - a.y * b.y, a.x * b.y + a.y * b.x);
}

// forward radix-4 butterfly (w_4 = -i)
__device__ __forceinline__ void bfly4(float2 z0, float2 z1, float2 z2, float2 z3,
                                      float2& o0, float2& o1, float2& o2, float2& o3) {
  float2 e0 = make_float2(z0.x + z2.x, z0.y + z2.y);
  float2 e1 = make_float2(z0.x - z2.x, z0.y - z2.y);
  float2 e2 = make_float2(z1.x + z3.x, z1.y + z3.y);
  float2 e3 = make_float2(z1.x - z3.x, z1.y - z3.y);
  o0 = make_float2(e0.x + e2.x, e0.y + e2.y);
  o2 = make_float2(e0.x - e2.x, e0.y - e2.y);
  o1 = make_float2(e1.x + e3.y, e1.y - e3.x);   // e1 - i*e3
  o3 = make_float2(e1.x - e3.y, e1.y + e3.x);   // e1 + i*e3
}

#define PIDX(i) ((i) + ((i) >> 3))

// ---------------------------------------------------------------- tables
__global__ void setup_kernel(float2* __restrict__ Wm, float2* __restrict__ Wpack,
                             float2* __restrict__ W512, float* __restrict__ hann) {
  int i = blockIdx.x * blockDim.x + threadIdx.x;
  if (i < M_HALF) {
    double th = 2.0 * PI_D * (double)i / (double)M_HALF;   // exp(+i th): inverse FFT
    double s, c; sincos(th, &s, &c);
    Wm[i] = make_float2((float)c, (float)s);
    double th2 = PI_D * (double)i / (double)M_HALF;        // 2*pi*i/96000
    double s2, c2; sincos(th2, &s2, &c2);
    Wpack[i] = make_float2((float)c2, (float)s2);
  }
  if (i < 512) {
    double th = -2.0 * PI_D * (double)i / 512.0;           // forward FFT
    double s, c; sincos(th, &s, &c);
    W512[i] = make_float2((float)c, (float)s);
    hann[i] = (float)(0.5 * (1.0 - cos(2.0 * PI_D * (double)i / 512.0)));
  }
}

// ------------------------------------------------- pack: X (half spec) -> Zf
__global__ __launch_bounds__(256) void pack_kernel(
    const float* __restrict__ tre, const float* __restrict__ tim,
    const float* __restrict__ are, const float* __restrict__ aim,
    float2* __restrict__ A, const float2* __restrict__ Wpack, int b0, int c) {
  int idx = blockIdx.x * blockDim.x + threadIdx.x;
  int total = 2 * c * M_HALF;
  if (idx >= total) return;
  int row = idx / M_HALF;
  int k = idx - row * M_HALF;
  int isA = row >= c;
  int b = b0 + (isA ? row - c : row);
  const float* re = isA ? are : tre;
  const float* im = isA ? aim : tim;
  const float* rr = re + (size_t)b * NFREQ;
  const float* ii = im + (size_t)b * NFREQ;
  float xr = rr[k];
  float xi = (k == 0) ? 0.f : ii[k];          // c2r drops Im at DC
  int mk = M_HALF - k;                         // in (0, M]
  float yr = rr[mk];
  float yi = (mk == M_HALF) ? 0.f : ii[mk];    // c2r drops Im at Nyquist
  float Er = 0.5f * (xr + yr);
  float Ei = 0.5f * (xi - yi);
  float Dr = 0.5f * (xr - yr);
  float Di = 0.5f * (xi + yi);
  float2 wp = Wpack[k];
  float tr = wp.x * Dr - wp.y * Di;
  float ti = wp.x * Di + wp.y * Dr;
  const float sc = 1.0f / (float)M_HALF;
  A[(size_t)row * M_HALF + k] = make_float2((Er - ti) * sc, (Ei + tr) * sc);
}

// --------------------------------------- mixed-radix Stockham IDFT stage (DIF)
template <int R, int S, int NN>
__global__ __launch_bounds__(256) void stage_kernel(
    const float2* __restrict__ x, float2* __restrict__ y,
    const float2* __restrict__ Wm, int rows) {
  constexpr int MM = NN / R;
  constexpr int ITEMS = M_HALF / R;
  int idx = blockIdx.x * blockDim.x + threadIdx.x;
  if (idx >= rows * ITEMS) return;
  int row = idx / ITEMS;
  int t = idx - row * ITEMS;
  int q = t % S;
  int p = t / S;
  const float2* xr = x + (size_t)row * M_HALF;
  float2* yr = y + (size_t)row * M_HALF;
  float2 a[R];
#pragma unroll
  for (int j = 0; j < R; ++j) a[j] = xr[q + S * (p + MM * j)];
  float2 wr[R];
#pragma unroll
  for (int t2 = 0; t2 < R; ++t2) wr[t2] = Wm[t2 * (M_HALF / R)];
  float2 twb = Wm[(size_t)p * (M_HALF / NN)];
  float2 tw = make_float2(1.f, 0.f);
#pragma unroll
  for (int u = 0; u < R; ++u) {
    float2 acc = a[0];
#pragma unroll
    for (int j = 1; j < R; ++j) {
      float2 w = wr[(u * j) % R];
      acc.x += a[j].x * w.x - a[j].y * w.y;
      acc.y += a[j].x * w.y + a[j].y * w.x;
    }
    acc = cmulf(acc, tw);
    yr[q + S * (R * p + u)] = acc;
    tw = cmulf(tw, twb);
  }
}

// ------------------------------------------------- STFT: real-512 via complex-256
// block = 256 threads = 4 waves; each wave handles FPW consecutive frames.
__global__ __launch_bounds__(256) void stft256_kernel(
    const float* __restrict__ xtime, float* __restrict__ P,
    const float2* __restrict__ W512, const float* __restrict__ hann) {
  __shared__ float2 lds[4][2][288];   // per-wave ping-pong, padded 256->288
  const int tid = threadIdx.x;
  const int wave = tid >> 6;
  const int l = tid & 63;
  const int row = blockIdx.y;
  const int frame0 = (blockIdx.x * 4 + wave) * FPW;

  float2* Abuf = lds[wave][0];
  float2* Bbuf = lds[wave][1];

  // hoisted per-wave constants
  const float2* hann2 = (const float2*)hann;
  float2 hw[4];
#pragma unroll
  for (int j = 0; j < 4; ++j) hw[j] = hann2[l + 64 * j];
  float2 t1[3], t2[3], t3[3];
  {
    int p2 = l >> 2, p3 = l >> 4;
#pragma unroll
    for (int u = 1; u <= 3; ++u) {
      t1[u - 1] = W512[2 * u * l];
      t2[u - 1] = W512[8 * u * p2];
      t3[u - 1] = W512[32 * u * p3];
    }
  }

  const float2* xrow = (const float2*)xtime + (size_t)row * 48000;

  for (int fi = 0; fi < FPW; ++fi) {
    const int fr = frame0 + fi;
    const bool active = (fr < NFRAMES);
    float2 z[4];
    if (active) {
      const float2* src = xrow + fr * 128;
#pragma unroll
      for (int j = 0; j < 4; ++j) {
        float2 v = src[l + 64 * j];
        z[j] = make_float2(v.x * hw[j].x, v.y * hw[j].y);
      }
    } else {
#pragma unroll
      for (int j = 0; j < 4; ++j) z[j] = make_float2(0.f, 0.f);
    }
    float2 o0, o1, o2, o3;
    // stage 1 (S=1, NN=256): registers, p = l
    bfly4(z[0], z[1], z[2], z[3], o0, o1, o2, o3);
    o1 = cmulf(o1, t1[0]); o2 = cmulf(o2, t1[1]); o3 = cmulf(o3, t1[2]);
    Abuf[PIDX(4 * l + 0)] = o0; Abuf[PIDX(4 * l + 1)] = o1;
    Abuf[PIDX(4 * l + 2)] = o2; Abuf[PIDX(4 * l + 3)] = o3;
    __syncthreads();
    // stage 2 (S=4, NN=64)
    {
      int q = l & 3, p = l >> 2;
      float2 a0 = Abuf[PIDX(q + 4 * p)];
      float2 a1 = Abuf[PIDX(q + 4 * (p + 16))];
      float2 a2 = Abuf[PIDX(q + 4 * (p + 32))];
      float2 a3 = Abuf[PIDX(q + 4 * (p + 48))];
      bfly4(a0, a1, a2, a3, o0, o1, o2, o3);
      o1 = cmulf(o1, t2[0]); o2 = cmulf(o2, t2[1]); o3 = cmulf(o3, t2[2]);
      int wb = q + 16 * p;
      Bbuf[PIDX(wb)] = o0; Bbuf[PIDX(wb + 4)] = o1;
      Bbuf[PIDX(wb + 8)] = o2; Bbuf[PIDX(wb + 12)] = o3;
    }
    __syncthreads();
    // stage 3 (S=16, NN=16)
    {
      int q = l & 15, p = l >> 4;
      float2 a0 = Bbuf[PIDX(q + 16 * p)];
      float2 a1 = Bbuf[PIDX(q + 16 * (p + 4))];
      float2 a2 = Bbuf[PIDX(q + 16 * (p + 8))];
      float2 a3 = Bbuf[PIDX(q + 16 * (p + 12))];
      bfly4(a0, a1, a2, a3, o0, o1, o2, o3);
      o1 = cmulf(o1, t3[0]); o2 = cmulf(o2, t3[1]); o3 = cmulf(o3, t3[2]);
      int wb = q + 64 * p;
      Abuf[PIDX(wb)] = o0; Abuf[PIDX(wb + 16)] = o1;
      Abuf[PIDX(wb + 32)] = o2; Abuf[PIDX(wb + 48)] = o3;
    }
    __syncthreads();
    // stage 4 (S=64, NN=4): no twiddle
    {
      float2 a0 = Abuf[PIDX(l)];
      float2 a1 = Abuf[PIDX(l + 64)];
      float2 a2 = Abuf[PIDX(l + 128)];
      float2 a3 = Abuf[PIDX(l + 192)];
      bfly4(a0, a1, a2, a3, o0, o1, o2, o3);
      Bbuf[PIDX(l)] = o0; Bbuf[PIDX(l + 64)] = o1;
      Bbuf[PIDX(l + 128)] = o2; Bbuf[PIDX(l + 192)] = o3;
    }
    __syncthreads();
    // unpack real-FFT bins + power
    if (active) {
      float* Prow = P + ((size_t)row * NFRAMES + fr) * NBINS;
      for (int k = l; k <= 256; k += 64) {
        float2 Zk = Bbuf[PIDX(k & 255)];
        float2 Zm = Bbuf[PIDX((256 - k) & 255)];
        float2 E  = make_float2(0.5f * (Zk.x + Zm.x), 0.5f * (Zk.y - Zm.y));
        float2 Op = make_float2(Zk.x - Zm.x, Zk.y + Zm.y);   // Zk - conj(Zm)
        float2 Od = make_float2(0.5f * Op.y, -0.5f * Op.x);  // (-i/2)*Op
        float2 W  = W512[k];
        float2 X  = make_float2(E.x + W.x * Od.x - W.y * Od.y,
                                E.y + W.x * Od.y + W.y * Od.x);
        Prow[k] = X.x * X.x + X.y * X.y;
      }
    }
    __syncthreads();
  }
}

// ---------------------------------- EDR phase A: per-group partial sums
__global__ __launch_bounds__(256) void edrA_kernel(const float* __restrict__ P,
                                                   float* __restrict__ part) {
  const int r = blockIdx.x;
  const int g = blockIdx.y;
  const float* Pr = P + (size_t)r * (NFRAMES * NBINS);
  for (int bin = threadIdx.x; bin < NBINS; bin += 256) {
    float s = 0.f;
    const int m0 = g * GLEN;
    for (int m = m0; m < m0 + GLEN; ++m) s += Pr[m * NBINS + bin];
    part[((size_t)r * NG + g) * NBINS + bin] = s;
  }
}

// ------------------- EDR phase B: suffix offsets + in-group chain + reduction
__global__ __launch_bounds__(256) void edrB_kernel(const float* __restrict__ P,
                                                   const float* __restrict__ part,
                                                   double* __restrict__ accum, int c) {
  const int b = blockIdx.x;
  const int g = blockIdx.y;
  const float* Pt = P + (size_t)b * (NFRAMES * NBINS);
  const float* Pa = P + (size_t)(b + c) * (NFRAMES * NBINS);
  const float* qt = part + (size_t)b * NG * NBINS;
  const float* qa = part + (size_t)(b + c) * NG * NBINS;
  float sn = 0.f, sd = 0.f;
  for (int bin = threadIdx.x; bin < NBINS; bin += 256) {
    float ct = 0.f, ca = 0.f;
    for (int g2 = g + 1; g2 < NG; ++g2) {
      ct += qt[g2 * NBINS + bin];
      ca += qa[g2 * NBINS + bin];
    }
    const int m0 = g * GLEN;
    for (int m = m0 + GLEN - 1; m >= m0; --m) {
      ct += Pt[m * NBINS + bin];
      ca += Pa[m * NBINS + bin];
      float lt = 10.f * log10f(ct);
      float la = 10.f * log10f(ca);
      sn += fabsf(lt - la);
      sd += fabsf(lt);
    }
  }
#pragma unroll
  for (int off = 32; off > 0; off >>= 1) {
    sn += __shfl_down(sn, off, 64);
    sd += __shfl_down(sd, off, 64);
  }
  __shared__ float wsn[4], wsd[4];
  const int wave = threadIdx.x >> 6;
  if ((threadIdx.x & 63) == 0) { wsn[wave] = sn; wsd[wave] = sd; }
  __syncthreads();
  if (threadIdx.x == 0) {
    float tn = 0.f, td = 0.f;
#pragma unroll
    for (int w = 0; w < 4; ++w) { tn += wsn[w]; td += wsd[w]; }
    int slot = (blockIdx.x * NG + blockIdx.y) & 63;
    atomicAdd(&accum[slot], (double)tn);
    atomicAdd(&accum[64 + slot], (double)td);
  }
}

__global__ void final_kernel(const double* __restrict__ accum, float* __restrict__ out) {
  double n = 0.0, d = 0.0;
  for (int i = 0; i < 64; ++i) { n += accum[i]; d += accum[64 + i]; }
  out[0] = (float)(n / d);
}

// ---------------------------------------------------------------- launcher
extern "C" void kernel_launch(void* const* d_in, const int* in_sizes, int n_in,
                              void* d_out, int out_size, void* d_ws, size_t ws_size,
                              hipStream_t stream) {
  const float* tre = (const float*)d_in[0];
  const float* tim = (const float*)d_in[1];
  const float* are = (const float*)d_in[2];
  const float* aim = (const float*)d_in[3];
  float* out = (float*)d_out;

  char* base = (char*)d_ws;
  size_t off = 0;
  auto take = [&](size_t bytes) -> char* {
    char* p = base + off;
    off += (bytes + 255) & ~(size_t)255;
    return p;
  };
  float2* Wm    = (float2*)take((size_t)M_HALF * sizeof(float2));
  float2* Wpack = (float2*)take((size_t)M_HALF * sizeof(float2));
  float2* W512  = (float2*)take(512 * sizeof(float2));
  float*  hann  = (float*)take(512 * sizeof(float));
  double* accum = (double*)take(128 * sizeof(double));
  size_t fixed = off;

  // per-batch-unit workspace: A (irfft ping), B/P (pong + power), part (EDR partials)
  const size_t perA    = (size_t)2 * M_HALF * sizeof(float2);       // 768000
  const size_t perP    = (size_t)2 * NFRAMES * NBINS * sizeof(float); // 768944 (>= perA pong)
  const size_t perPart = (size_t)2 * NG * NBINS * sizeof(float);    // 22616
  int c = 1;
  const int cands[8] = {128, 64, 32, 16, 8, 4, 2, 1};
  for (int ci = 0; ci < 8; ++ci) {
    size_t need = fixed + ((cands[ci] * perA + 255) & ~(size_t)255)
                        + ((cands[ci] * perP + 255) & ~(size_t)255)
                        + ((cands[ci] * perPart + 255) & ~(size_t)255);
    if (need <= ws_size) { c = cands[ci]; break; }
  }
  float2* A  = (float2*)take((size_t)c * perA);
  char*   BP = take((size_t)c * perP);
  float*  part = (float*)take((size_t)c * perPart);
  float2* Bb = (float2*)BP;  // FFT ping-pong partner
  float*  P  = (float*)BP;   // power spectra (aliases Bb; Bb dead by then)

  setup_kernel<<<(M_HALF + 255) / 256, 256, 0, stream>>>(Wm, Wpack, W512, hann);
  hipMemsetAsync(accum, 0, 128 * sizeof(double), stream);

  for (int b0 = 0; b0 < BATCH; b0 += c) {
    int rows = 2 * c;
    int tot = rows * M_HALF;
    pack_kernel<<<(tot + 255) / 256, 256, 0, stream>>>(tre, tim, are, aim, A, Wpack, b0, c);
    // 48000 = 15 * 16 * 10 * 20 ; Stockham ping-pong A->B->A->B->A
    {
      int items = rows * (M_HALF / 15);
      stage_kernel<15, 1, 48000><<<(items + 255) / 256, 256, 0, stream>>>(A, Bb, Wm, rows);
    }
    {
      int items = rows * (M_HALF / 16);
      stage_kernel<16, 15, 3200><<<(items + 255) / 256, 256, 0, stream>>>(Bb, A, Wm, rows);
    }
    {
      int items = rows * (M_HALF / 10);
      stage_kernel<10, 240, 200><<<(items + 255) / 256, 256, 0, stream>>>(A, Bb, Wm, rows);
    }
    {
      int items = rows * (M_HALF / 20);
      stage_kernel<20, 2400, 20><<<(items + 255) / 256, 256, 0, stream>>>(Bb, A, Wm, rows);
    }
    // A (interleaved re/im of z[t]) IS the real time signal x[t] of length 96000
    {
      dim3 grid((NFRAMES + 4 * FPW - 1) / (4 * FPW), rows);
      stft256_kernel<<<grid, 256, 0, stream>>>((const float*)A, P, W512, hann);
    }
    edrA_kernel<<<dim3(rows, NG), 256, 0, stream>>>(P, part);
    edrB_kernel<<<dim3(c, NG), 256, 0, stream>>>(P, part, accum, c);
  }
  final_kernel<<<1, 1, 0, stream>>>(accum, out);
}

// Round 3
// 451.938 us; speedup vs baseline: 1.3880x; 1.0809x over previous
//
#include <hip/hip_runtime.h>
#include <math.h>

#define BATCH   128
#define NFREQ   96000      // input row length (freq pts); irfft length
#define M_HALF  48000      // complex IDFT length
#define NFRAMES 374
#define NBINS   257
#define NG      11         // frame groups for segmented reverse cumsum
#define GLEN    34         // 11 * 34 = 374 exactly
#define FPW     4          // frames per wave in stft kernel

#define CS1 246            // LDS column stride, kernel1 (240-pt), bank-spread
#define CS2 206            // LDS column stride, kernel2 (200-pt)

#define PI_D 3.14159265358979323846

// wave-local LDS sync: all 64 lanes of a wave run in lockstep; we only need
// prior ds_writes complete + a compiler barrier. Valid only when the LDS
// region is wave-private.
#define WAVE_SYNC() __asm__ volatile("s_waitcnt lgkmcnt(0)" ::: "memory")

__device__ __forceinline__ float2 cmulf(float2 a, float2 b) {
  return make_float2(a.x * b.x - a.y * b.y, a.x * b.y + a.y * b.x);
}

// forward radix-4 butterfly (w4 = -i)
__device__ __forceinline__ void bfly4(float2 z0, float2 z1, float2 z2, float2 z3,
                                      float2& o0, float2& o1, float2& o2, float2& o3) {
  float2 e0 = make_float2(z0.x + z2.x, z0.y + z2.y);
  float2 e1 = make_float2(z0.x - z2.x, z0.y - z2.y);
  float2 e2 = make_float2(z1.x + z3.x, z1.y + z3.y);
  float2 e3 = make_float2(z1.x - z3.x, z1.y - z3.y);
  o0 = make_float2(e0.x + e2.x, e0.y + e2.y);
  o2 = make_float2(e0.x - e2.x, e0.y - e2.y);
  o1 = make_float2(e1.x + e3.y, e1.y - e3.x);   // e1 - i*e3
  o3 = make_float2(e1.x - e3.y, e1.y + e3.x);   // e1 + i*e3
}

// inverse radix-4 butterfly (w4 = +i)
__device__ __forceinline__ void bfly4i(float2 z0, float2 z1, float2 z2, float2 z3,
                                       float2& o0, float2& o1, float2& o2, float2& o3) {
  float2 e0 = make_float2(z0.x + z2.x, z0.y + z2.y);
  float2 e1 = make_float2(z0.x - z2.x, z0.y - z2.y);
  float2 e2 = make_float2(z1.x + z3.x, z1.y + z3.y);
  float2 e3 = make_float2(z1.x - z3.x, z1.y - z3.y);
  o0 = make_float2(e0.x + e2.x, e0.y + e2.y);
  o2 = make_float2(e0.x - e2.x, e0.y - e2.y);
  o1 = make_float2(e1.x - e3.y, e1.y + e3.x);   // e1 + i*e3
  o3 = make_float2(e1.x + e3.y, e1.y - e3.x);   // e1 - i*e3
}

#define PIDX(i) ((i) + ((i) >> 3))

// ---------------------------------------------------------------- tables
__global__ void setup_kernel(float2* __restrict__ Wm, float2* __restrict__ Wpack,
                             float2* __restrict__ W512, float* __restrict__ hann,
                             float2* __restrict__ W240, float2* __restrict__ W200,
                             float2* __restrict__ Wp240) {
  int i = blockIdx.x * blockDim.x + threadIdx.x;
  if (i < M_HALF) {
    double th = 2.0 * PI_D * (double)i / (double)M_HALF;   // e^{+2pi i k/48000}
    double s, c; sincos(th, &s, &c);
    Wm[i] = make_float2((float)c, (float)s);
    double th2 = PI_D * (double)i / (double)M_HALF;        // e^{+i pi k/48000}
    double s2, c2; sincos(th2, &s2, &c2);
    Wpack[i] = make_float2((float)c2, (float)s2);
  }
  if (i < 512) {
    double th = -2.0 * PI_D * (double)i / 512.0;           // forward FFT
    double s, c; sincos(th, &s, &c);
    W512[i] = make_float2((float)c, (float)s);
    hann[i] = (float)(0.5 * (1.0 - cos(2.0 * PI_D * (double)i / 512.0)));
  }
  if (i < 240) {
    double th = 2.0 * PI_D * (double)i / 240.0;
    double s, c; sincos(th, &s, &c);
    W240[i] = make_float2((float)c, (float)s);
    double th2 = PI_D * (double)i / 240.0;                 // e^{+i pi k2/240}
    double s2, c2; sincos(th2, &s2, &c2);
    Wp240[i] = make_float2((float)c2, (float)s2);
  }
  if (i < 200) {
    double th = 2.0 * PI_D * (double)i / 200.0;
    double s, c; sincos(th, &s, &c);
    W200[i] = make_float2((float)c, (float)s);
  }
}

// ---------------------------------------------------------------------------
// kernel1: fused pack + 240-pt IDFT (over k2) + CT twiddle, transposed store.
// Four-step: N=48000=200x240, k=k1+200*k2, n=n2+240*n1.
// G[row][n2][k1] = e^{2pi i k1 n2/48000} * sum_k2 Zf[k1+200 k2] e^{2pi i k2 n2/240}
// Block: 8 consecutive k1 (tile), one row. 25 tiles x rows.
// ---------------------------------------------------------------------------
__global__ __launch_bounds__(256) void k1_kernel(
    const float* __restrict__ tre, const float* __restrict__ tim,
    const float* __restrict__ are, const float* __restrict__ aim,
    float2* __restrict__ G, const float2* __restrict__ Wm,
    const float2* __restrict__ Wpack, const float2* __restrict__ Wp240,
    const float2* __restrict__ W240, int b0, int c) {
  __shared__ float2 LA[8 * CS1];
  __shared__ float2 LB[8 * CS1];
  const int tid = threadIdx.x;
  const int row = blockIdx.y;
  const int K0 = blockIdx.x * 8;

  const int isA = row >= c;
  const int b = b0 + (isA ? row - c : row);
  const float* rr = (isA ? are : tre) + (size_t)b * NFREQ;
  const float* ii = (isA ? aim : tim) + (size_t)b * NFREQ;

  // ---- load + pack: Zf[k] = (E + i*Wpack[k]*D)/M,  k = K0+k1o+200*k2
  {
    const int k1o = tid & 7;
    const float2 wpa = Wpack[K0 + k1o];
    const float sc = 1.0f / (float)M_HALF;
    for (int e = tid; e < 8 * 240; e += 256) {
      int k2 = e >> 3;
      int k = K0 + k1o + 200 * k2;
      float xr = rr[k];
      float xi = (k == 0) ? 0.f : ii[k];
      int mk = M_HALF - k;
      float yr = rr[mk];
      float yi = (k == 0) ? 0.f : ii[mk];   // mk==48000 iff k==0 (Nyquist)
      float Er = 0.5f * (xr + yr);
      float Ei = 0.5f * (xi - yi);
      float Dr = 0.5f * (xr - yr);
      float Di = 0.5f * (xi + yi);
      float2 wp = cmulf(wpa, Wp240[k2]);
      float tr = wp.x * Dr - wp.y * Di;
      float ti = wp.x * Di + wp.y * Dr;
      LA[k1o * CS1 + k2] = make_float2((Er - ti) * sc, (Ei + tr) * sc);
    }
  }
  __syncthreads();
  // ---- stage <R=4,S=1,NN=240>: in p+60j -> out 4p+u, tw W240^{up}
  for (int e = tid; e < 8 * 60; e += 256) {
    int col = e & 7, p = e >> 3;
    const float2* in = LA + col * CS1;
    float2 o0, o1, o2, o3;
    bfly4i(in[p], in[p + 60], in[p + 120], in[p + 180], o0, o1, o2, o3);
    o1 = cmulf(o1, W240[p]);
    o2 = cmulf(o2, W240[2 * p]);
    o3 = cmulf(o3, W240[3 * p]);
    float2* out = LB + col * CS1 + 4 * p;
    out[0] = o0; out[1] = o1; out[2] = o2; out[3] = o3;
  }
  __syncthreads();
  // ---- stage <R=4,S=4,NN=60>: q=t&3,p=t>>2; in q+4(p+15j) -> q+4(4p+u), tw W60^{up}=W240[4up]
  for (int e = tid; e < 8 * 60; e += 256) {
    int col = e & 7, t = e >> 3;
    int q = t & 3, p = t >> 2;
    const float2* in = LB + col * CS1;
    float2 o0, o1, o2, o3;
    bfly4i(in[q + 4 * p], in[q + 4 * (p + 15)], in[q + 4 * (p + 30)],
           in[q + 4 * (p + 45)], o0, o1, o2, o3);
    o1 = cmulf(o1, W240[4 * p]);
    o2 = cmulf(o2, W240[8 * p]);
    o3 = cmulf(o3, W240[12 * p]);
    float2* out = LA + col * CS1 + q;
    out[4 * (4 * p + 0)] = o0; out[4 * (4 * p + 1)] = o1;
    out[4 * (4 * p + 2)] = o2; out[4 * (4 * p + 3)] = o3;
  }
  __syncthreads();
  // ---- stage <R=15,S=16,NN=15>: q=t; in q+16j -> q+16u, no tw
  {
    float2 w15[15];
#pragma unroll
    for (int m = 0; m < 15; ++m) w15[m] = W240[16 * m];
    for (int e = tid; e < 8 * 16; e += 256) {
      int col = e & 7, q = e >> 3;
      const float2* in = LA + col * CS1 + q;
      float2 a[15];
#pragma unroll
      for (int j = 0; j < 15; ++j) a[j] = in[16 * j];
      float2* out = LB + col * CS1 + q;
#pragma unroll
      for (int u = 0; u < 15; ++u) {
        float2 acc = a[0];
#pragma unroll
        for (int j = 1; j < 15; ++j) {
          float2 w = w15[(u * j) % 15];
          acc.x += a[j].x * w.x - a[j].y * w.y;
          acc.y += a[j].x * w.y + a[j].y * w.x;
        }
        out[16 * u] = acc;
      }
    }
  }
  __syncthreads();
  // ---- CT twiddle (incremental) + transposed store G[n2*200 + k1]
  {
    const int col = tid & 7;
    const int k1 = K0 + col;
    int n2 = tid >> 3;                       // [0,32)
    float2 tw = Wm[k1 * n2];                 // max 199*31 < 48000
    const float2 twstep = Wm[32 * k1];       // max 32*199 < 48000
    float2* Grow = G + (size_t)row * M_HALF;
    const float2* in = LB + col * CS1;
    for (; n2 < 240; n2 += 32) {
      Grow[(size_t)n2 * 200 + k1] = cmulf(in[n2], tw);
      tw = cmulf(tw, twstep);
    }
  }
}

// ---------------------------------------------------------------------------
// kernel2: 200-pt IDFT over k1 (contiguous reads), scatter store to time order.
// x[n2 + 240*n1] = sum_k1 G[n2][k1] e^{2pi i k1 n1/200}
// Block: 8 consecutive n2, one row. 30 tiles x rows.
// ---------------------------------------------------------------------------
__global__ __launch_bounds__(256) void k2_kernel(
    const float2* __restrict__ G, float2* __restrict__ X,
    const float2* __restrict__ W200) {
  __shared__ float2 LA[8 * CS2];
  __shared__ float2 LB[8 * CS2];
  const int tid = threadIdx.x;
  const int row = blockIdx.y;
  const int N20 = blockIdx.x * 8;
  const float2* Grow = G + (size_t)row * M_HALF;

  for (int e = tid; e < 8 * 200; e += 256) {
    int n2o = e / 200;
    int k1 = e - n2o * 200;
    LA[n2o * CS2 + k1] = Grow[(size_t)(N20 + n2o) * 200 + k1];
  }
  __syncthreads();
  // ---- stage <R=4,S=1,NN=200>: in p+50j -> 4p+u, tw W200^{up}
  for (int e = tid; e < 8 * 50; e += 256) {
    int col = e & 7, p = e >> 3;
    const float2* in = LA + col * CS2;
    float2 o0, o1, o2, o3;
    bfly4i(in[p], in[p + 50], in[p + 100], in[p + 150], o0, o1, o2, o3);
    o1 = cmulf(o1, W200[p]);
    o2 = cmulf(o2, W200[2 * p]);
    o3 = cmulf(o3, W200[3 * p]);
    float2* out = LB + col * CS2 + 4 * p;
    out[0] = o0; out[1] = o1; out[2] = o2; out[3] = o3;
  }
  __syncthreads();
  // ---- stage <R=5,S=4,NN=50>: q=t&3,p=t>>2 in [0,10); in q+4(p+10j) -> q+4(5p+u), tw W50^{up}=W200[4up]
  {
    float2 w5[5];
#pragma unroll
    for (int m = 0; m < 5; ++m) w5[m] = W200[40 * m];
    for (int e = tid; e < 8 * 40; e += 256) {
      int col = e & 7, t = e >> 3;
      int q = t & 3, p = t >> 2;
      const float2* in = LB + col * CS2 + q;
      float2 a[5];
#pragma unroll
      for (int j = 0; j < 5; ++j) a[j] = in[4 * (p + 10 * j)];
      float2* out = LA + col * CS2 + q;
#pragma unroll
      for (int u = 0; u < 5; ++u) {
        float2 acc = a[0];
#pragma unroll
        for (int j = 1; j < 5; ++j) {
          float2 w = w5[(u * j) % 5];
          acc.x += a[j].x * w.x - a[j].y * w.y;
          acc.y += a[j].x * w.y + a[j].y * w.x;
        }
        acc = cmulf(acc, W200[4 * u * p]);
        out[4 * (5 * p + u)] = acc;
      }
    }
  }
  __syncthreads();
  // ---- stage <R=10,S=20,NN=10>: q=t in [0,20); in q+20j -> q+20u, no tw
  {
    float2 w10[10];
#pragma unroll
    for (int m = 0; m < 10; ++m) w10[m] = W200[20 * m];
    for (int e = tid; e < 8 * 20; e += 256) {
      int col = e & 7, q = e >> 3;
      const float2* in = LA + col * CS2 + q;
      float2 a[10];
#pragma unroll
      for (int j = 0; j < 10; ++j) a[j] = in[20 * j];
      float2* out = LB + col * CS2 + q;
#pragma unroll
      for (int u = 0; u < 10; ++u) {
        float2 acc = a[0];
#pragma unroll
        for (int j = 1; j < 10; ++j) {
          float2 w = w10[(u * j) % 10];
          acc.x += a[j].x * w.x - a[j].y * w.y;
          acc.y += a[j].x * w.y + a[j].y * w.x;
        }
        out[20 * u] = acc;
      }
    }
  }
  __syncthreads();
  // ---- store: x[(N20+n2o) + 240*n1] = LB[n2o][n1]
  {
    const int n2o = tid & 7;
    float2* Xrow = X + (size_t)row * M_HALF + (N20 + n2o);
    const float2* in = LB + n2o * CS2;
    for (int n1 = tid >> 3; n1 < 200; n1 += 32)
      Xrow[240 * n1] = in[n1];
  }
}

// ------------------------------------------------- STFT: real-512 via complex-256
// block = 256 threads = 4 waves; each wave handles FPW consecutive frames.
// LDS regions are wave-private -> wave-local syncs only.
__global__ __launch_bounds__(256) void stft256_kernel(
    const float* __restrict__ xtime, float* __restrict__ P,
    const float2* __restrict__ W512, const float* __restrict__ hann) {
  __shared__ float2 lds[4][2][288];   // per-wave ping-pong, padded 256->288
  const int tid = threadIdx.x;
  const int wave = tid >> 6;
  const int l = tid & 63;
  const int row = blockIdx.y;
  const int frame0 = (blockIdx.x * 4 + wave) * FPW;

  float2* Abuf = lds[wave][0];
  float2* Bbuf = lds[wave][1];

  const float2* hann2 = (const float2*)hann;
  float2 hw[4];
#pragma unroll
  for (int j = 0; j < 4; ++j) hw[j] = hann2[l + 64 * j];
  float2 t1[3], t2[3], t3[3];
  {
    int p2 = l >> 2, p3 = l >> 4;
#pragma unroll
    for (int u = 1; u <= 3; ++u) {
      t1[u - 1] = W512[2 * u * l];
      t2[u - 1] = W512[8 * u * p2];
      t3[u - 1] = W512[32 * u * p3];
    }
  }

  const float2* xrow = (const float2*)xtime + (size_t)row * 48000;

  for (int fi = 0; fi < FPW; ++fi) {
    const int fr = frame0 + fi;
    const bool active = (fr < NFRAMES);
    float2 z[4];
    if (active) {
      const float2* src = xrow + fr * 128;
#pragma unroll
      for (int j = 0; j < 4; ++j) {
        float2 v = src[l + 64 * j];
        z[j] = make_float2(v.x * hw[j].x, v.y * hw[j].y);
      }
    } else {
#pragma unroll
      for (int j = 0; j < 4; ++j) z[j] = make_float2(0.f, 0.f);
    }
    float2 o0, o1, o2, o3;
    bfly4(z[0], z[1], z[2], z[3], o0, o1, o2, o3);
    o1 = cmulf(o1, t1[0]); o2 = cmulf(o2, t1[1]); o3 = cmulf(o3, t1[2]);
    Abuf[PIDX(4 * l + 0)] = o0; Abuf[PIDX(4 * l + 1)] = o1;
    Abuf[PIDX(4 * l + 2)] = o2; Abuf[PIDX(4 * l + 3)] = o3;
    WAVE_SYNC();
    {
      int q = l & 3, p = l >> 2;
      float2 a0 = Abuf[PIDX(q + 4 * p)];
      float2 a1 = Abuf[PIDX(q + 4 * (p + 16))];
      float2 a2 = Abuf[PIDX(q + 4 * (p + 32))];
      float2 a3 = Abuf[PIDX(q + 4 * (p + 48))];
      bfly4(a0, a1, a2, a3, o0, o1, o2, o3);
      o1 = cmulf(o1, t2[0]); o2 = cmulf(o2, t2[1]); o3 = cmulf(o3, t2[2]);
      int wb = q + 16 * p;
      Bbuf[PIDX(wb)] = o0; Bbuf[PIDX(wb + 4)] = o1;
      Bbuf[PIDX(wb + 8)] = o2; Bbuf[PIDX(wb + 12)] = o3;
    }
    WAVE_SYNC();
    {
      int q = l & 15, p = l >> 4;
      float2 a0 = Bbuf[PIDX(q + 16 * p)];
      float2 a1 = Bbuf[PIDX(q + 16 * (p + 4))];
      float2 a2 = Bbuf[PIDX(q + 16 * (p + 8))];
      float2 a3 = Bbuf[PIDX(q + 16 * (p + 12))];
      bfly4(a0, a1, a2, a3, o0, o1, o2, o3);
      o1 = cmulf(o1, t3[0]); o2 = cmulf(o2, t3[1]); o3 = cmulf(o3, t3[2]);
      int wb = q + 64 * p;
      Abuf[PIDX(wb)] = o0; Abuf[PIDX(wb + 16)] = o1;
      Abuf[PIDX(wb + 32)] = o2; Abuf[PIDX(wb + 48)] = o3;
    }
    WAVE_SYNC();
    {
      float2 a0 = Abuf[PIDX(l)];
      float2 a1 = Abuf[PIDX(l + 64)];
      float2 a2 = Abuf[PIDX(l + 128)];
      float2 a3 = Abuf[PIDX(l + 192)];
      bfly4(a0, a1, a2, a3, o0, o1, o2, o3);
      Bbuf[PIDX(l)] = o0; Bbuf[PIDX(l + 64)] = o1;
      Bbuf[PIDX(l + 128)] = o2; Bbuf[PIDX(l + 192)] = o3;
    }
    WAVE_SYNC();
    if (active) {
      float* Prow = P + ((size_t)row * NFRAMES + fr) * NBINS;
      for (int k = l; k <= 256; k += 64) {
        float2 Zk = Bbuf[PIDX(k & 255)];
        float2 Zm = Bbuf[PIDX((256 - k) & 255)];
        float2 E  = make_float2(0.5f * (Zk.x + Zm.x), 0.5f * (Zk.y - Zm.y));
        float2 Op = make_float2(Zk.x - Zm.x, Zk.y + Zm.y);
        float2 Od = make_float2(0.5f * Op.y, -0.5f * Op.x);
        float2 W  = W512[k];
        float2 Xb = make_float2(E.x + W.x * Od.x - W.y * Od.y,
                                E.y + W.x * Od.y + W.y * Od.x);
        Prow[k] = Xb.x * Xb.x + Xb.y * Xb.y;
      }
    }
    WAVE_SYNC();
  }
}

// ---------------------------------- EDR phase A: per-group partial sums
__global__ __launch_bounds__(256) void edrA_kernel(const float* __restrict__ P,
                                                   float* __restrict__ part) {
  const int r = blockIdx.x;
  const int g = blockIdx.y;
  const float* Pr = P + (size_t)r * (NFRAMES * NBINS);
  for (int bin = threadIdx.x; bin < NBINS; bin += 256) {
    float s = 0.f;
    const int m0 = g * GLEN;
    for (int m = m0; m < m0 + GLEN; ++m) s += Pr[m * NBINS + bin];
    part[((size_t)r * NG + g) * NBINS + bin] = s;
  }
}

// ------------------- EDR phase B: suffix offsets + in-group chain + reduction
__global__ __launch_bounds__(256) void edrB_kernel(const float* __restrict__ P,
                                                   const float* __restrict__ part,
                                                   double* __restrict__ accum, int c) {
  const int b = blockIdx.x;
  const int g = blockIdx.y;
  const float* Pt = P + (size_t)b * (NFRAMES * NBINS);
  const float* Pa = P + (size_t)(b + c) * (NFRAMES * NBINS);
  const float* qt = part + (size_t)b * NG * NBINS;
  const float* qa = part + (size_t)(b + c) * NG * NBINS;
  float sn = 0.f, sd = 0.f;
  for (int bin = threadIdx.x; bin < NBINS; bin += 256) {
    float ct = 0.f, ca = 0.f;
    for (int g2 = g + 1; g2 < NG; ++g2) {
      ct += qt[g2 * NBINS + bin];
      ca += qa[g2 * NBINS + bin];
    }
    const int m0 = g * GLEN;
    for (int m = m0 + GLEN - 1; m >= m0; --m) {
      ct += Pt[m * NBINS + bin];
      ca += Pa[m * NBINS + bin];
      float lt = 10.f * log10f(ct);
      float la = 10.f * log10f(ca);
      sn += fabsf(lt - la);
      sd += fabsf(lt);
    }
  }
#pragma unroll
  for (int off = 32; off > 0; off >>= 1) {
    sn += __shfl_down(sn, off, 64);
    sd += __shfl_down(sd, off, 64);
  }
  __shared__ float wsn[4], wsd[4];
  const int wave = threadIdx.x >> 6;
  if ((threadIdx.x & 63) == 0) { wsn[wave] = sn; wsd[wave] = sd; }
  __syncthreads();
  if (threadIdx.x == 0) {
    float tn = 0.f, td = 0.f;
#pragma unroll
    for (int w = 0; w < 4; ++w) { tn += wsn[w]; td += wsd[w]; }
    int slot = (blockIdx.x * NG + blockIdx.y) & 63;
    atomicAdd(&accum[slot], (double)tn);
    atomicAdd(&accum[64 + slot], (double)td);
  }
}

__global__ void final_kernel(const double* __restrict__ accum, float* __restrict__ out) {
  double n = 0.0, d = 0.0;
  for (int i = 0; i < 64; ++i) { n += accum[i]; d += accum[64 + i]; }
  out[0] = (float)(n / d);
}

// ---------------------------------------------------------------- launcher
extern "C" void kernel_launch(void* const* d_in, const int* in_sizes, int n_in,
                              void* d_out, int out_size, void* d_ws, size_t ws_size,
                              hipStream_t stream) {
  const float* tre = (const float*)d_in[0];
  const float* tim = (const float*)d_in[1];
  const float* are = (const float*)d_in[2];
  const float* aim = (const float*)d_in[3];
  float* out = (float*)d_out;

  char* base = (char*)d_ws;
  size_t off = 0;
  auto take = [&](size_t bytes) -> char* {
    char* p = base + off;
    off += (bytes + 255) & ~(size_t)255;
    return p;
  };
  float2* Wm    = (float2*)take((size_t)M_HALF * sizeof(float2));
  float2* Wpack = (float2*)take((size_t)M_HALF * sizeof(float2));
  float2* W512  = (float2*)take(512 * sizeof(float2));
  float*  hann  = (float*)take(512 * sizeof(float));
  float2* W240  = (float2*)take(240 * sizeof(float2));
  float2* W200  = (float2*)take(200 * sizeof(float2));
  float2* Wp240 = (float2*)take(240 * sizeof(float2));
  double* accum = (double*)take(128 * sizeof(double));
  size_t fixed = off;

  // per-batch-unit (2 rows): Z buffer, G/P alias buffer, EDR partials
  const size_t perA    = (size_t)2 * M_HALF * sizeof(float2);         // 768000 (Z)
  const size_t perP    = (size_t)2 * NFRAMES * NBINS * sizeof(float); // 768944 (G then P)
  const size_t perPart = (size_t)2 * NG * NBINS * sizeof(float);      // 22616
  int c = 1;
  const int cands[8] = {128, 64, 32, 16, 8, 4, 2, 1};
  for (int ci = 0; ci < 8; ++ci) {
    size_t need = fixed + ((cands[ci] * perA + 255) & ~(size_t)255)
                        + ((cands[ci] * perP + 255) & ~(size_t)255)
                        + ((cands[ci] * perPart + 255) & ~(size_t)255);
    if (need <= ws_size) { c = cands[ci]; break; }
  }
  float2* Z    = (float2*)take((size_t)c * perA);
  char*   BP   = take((size_t)c * perP);
  float*  part = (float*)take((size_t)c * perPart);
  float2* G = (float2*)BP;   // kernel1 output (CT intermediate)
  float*  P = (float*)BP;    // power spectra (aliases G; G dead after k2)

  setup_kernel<<<(M_HALF + 255) / 256, 256, 0, stream>>>(Wm, Wpack, W512, hann,
                                                         W240, W200, Wp240);
  hipMemsetAsync(accum, 0, 128 * sizeof(double), stream);

  for (int b0 = 0; b0 < BATCH; b0 += c) {
    int rows = 2 * c;
    k1_kernel<<<dim3(25, rows), 256, 0, stream>>>(tre, tim, are, aim, G, Wm,
                                                  Wpack, Wp240, W240, b0, c);
    k2_kernel<<<dim3(30, rows), 256, 0, stream>>>(G, Z, W200);
    {
      dim3 grid((NFRAMES + 4 * FPW - 1) / (4 * FPW), rows);
      stft256_kernel<<<grid, 256, 0, stream>>>((const float*)Z, P, W512, hann);
    }
    edrA_kernel<<<dim3(rows, NG), 256, 0, stream>>>(P, part);
    edrB_kernel<<<dim3(c, NG), 256, 0, stream>>>(P, part, accum, c);
  }
  final_kernel<<<1, 1, 0, stream>>>(accum, out);
}

// Round 4
// 448.041 us; speedup vs baseline: 1.4001x; 1.0087x over previous
//
#include <hip/hip_runtime.h>
#include <math.h>

#define BATCH   128
#define NFREQ   96000      // input row length (freq pts); irfft length
#define M_HALF  48000      // complex IDFT length
#define NFRAMES 374
#define NBINS   257
#define NG      11         // frame groups for segmented reverse cumsum
#define GLEN    34         // 11 * 34 = 374 exactly
#define FPW     4          // frames per wave in stft kernel

#define CS1 246            // LDS column stride, kernel1 (240-pt), bank-spread
#define CS2 206            // LDS column stride, kernel2 (200-pt)

#define PI_D 3.14159265358979323846

// wave-local LDS sync (LDS region wave-private; 64 lanes lockstep)
#define WAVE_SYNC() __asm__ volatile("s_waitcnt lgkmcnt(0)" ::: "memory")

__device__ __forceinline__ float2 cmulf(float2 a, float2 b) {
  return make_float2(a.x * b.x - a.y * b.y, a.x * b.y + a.y * b.x);
}

// forward radix-4 butterfly (w4 = -i)
__device__ __forceinline__ void bfly4(float2 z0, float2 z1, float2 z2, float2 z3,
                                      float2& o0, float2& o1, float2& o2, float2& o3) {
  float2 e0 = make_float2(z0.x + z2.x, z0.y + z2.y);
  float2 e1 = make_float2(z0.x - z2.x, z0.y - z2.y);
  float2 e2 = make_float2(z1.x + z3.x, z1.y + z3.y);
  float2 e3 = make_float2(z1.x - z3.x, z1.y - z3.y);
  o0 = make_float2(e0.x + e2.x, e0.y + e2.y);
  o2 = make_float2(e0.x - e2.x, e0.y - e2.y);
  o1 = make_float2(e1.x + e3.y, e1.y - e3.x);   // e1 - i*e3
  o3 = make_float2(e1.x - e3.y, e1.y + e3.x);   // e1 + i*e3
}

// inverse radix-4 butterfly (w4 = +i)
__device__ __forceinline__ void bfly4i(float2 z0, float2 z1, float2 z2, float2 z3,
                                       float2& o0, float2& o1, float2& o2, float2& o3) {
  float2 e0 = make_float2(z0.x + z2.x, z0.y + z2.y);
  float2 e1 = make_float2(z0.x - z2.x, z0.y - z2.y);
  float2 e2 = make_float2(z1.x + z3.x, z1.y + z3.y);
  float2 e3 = make_float2(z1.x - z3.x, z1.y - z3.y);
  o0 = make_float2(e0.x + e2.x, e0.y + e2.y);
  o2 = make_float2(e0.x - e2.x, e0.y - e2.y);
  o1 = make_float2(e1.x - e3.y, e1.y + e3.x);   // e1 + i*e3
  o3 = make_float2(e1.x + e3.y, e1.y - e3.x);   // e1 - i*e3
}

#define PIDX(i) ((i) + ((i) >> 3))

// ---------------------------------------------------------------- tables
__global__ void setup_kernel(float2* __restrict__ Wm, float2* __restrict__ Wpack,
                             float2* __restrict__ W512, float* __restrict__ hann,
                             float2* __restrict__ W240, float2* __restrict__ W200) {
  int i = blockIdx.x * blockDim.x + threadIdx.x;
  if (i < M_HALF) {
    double th = 2.0 * PI_D * (double)i / (double)M_HALF;   // e^{+2pi i k/48000}
    double s, c; sincos(th, &s, &c);
    Wm[i] = make_float2((float)c, (float)s);
    double th2 = PI_D * (double)i / (double)M_HALF;        // e^{+i pi k/48000}
    double s2, c2; sincos(th2, &s2, &c2);
    Wpack[i] = make_float2((float)c2, (float)s2);
  }
  if (i < 512) {
    double th = -2.0 * PI_D * (double)i / 512.0;           // forward FFT
    double s, c; sincos(th, &s, &c);
    W512[i] = make_float2((float)c, (float)s);
    hann[i] = (float)(0.5 * (1.0 - cos(2.0 * PI_D * (double)i / 512.0)));
  }
  if (i < 240) {
    double th = 2.0 * PI_D * (double)i / 240.0;
    double s, c; sincos(th, &s, &c);
    W240[i] = make_float2((float)c, (float)s);
  }
  if (i < 200) {
    double th = 2.0 * PI_D * (double)i / 200.0;
    double s, c; sincos(th, &s, &c);
    W200[i] = make_float2((float)c, (float)s);
  }
}

// ---------------------------------------------------------------------------
// pass0: fused pack + transpose.  Zf[k] = (E + i*Wpack[k]*D)/M from X[k],
// X[48000-k]; store k1-major: Zt[row][k1*240 + k2], k = k1 + 200*k2.
// Block: contiguous k span of 1600 (= 8 k2 x 200 k1). Loads fully coalesced
// (direct span ascending, mirror span descending), writes in 64B chunks.
// ---------------------------------------------------------------------------
__global__ __launch_bounds__(256) void packT_kernel(
    const float* __restrict__ tre, const float* __restrict__ tim,
    const float* __restrict__ are, const float* __restrict__ aim,
    float2* __restrict__ Zt, const float2* __restrict__ Wpack, int b0, int c) {
  __shared__ float dRe[1600], dIm[1600], mRe[1600], mIm[1600];
  const int tid = threadIdx.x;
  const int row = blockIdx.y;
  const int base = blockIdx.x * 1600;   // k in [base, base+1600)
  const int isA = row >= c;
  const int b = b0 + (isA ? row - c : row);
  const float* rr = (isA ? are : tre) + (size_t)b * NFREQ;
  const float* ii = (isA ? aim : tim) + (size_t)b * NFREQ;
  for (int j = tid; j < 1600; j += 256) {
    dRe[j] = rr[base + j];
    dIm[j] = ii[base + j];
    int mk = M_HALF - base - j;          // in [1, 48000]
    mRe[j] = rr[mk];
    mIm[j] = ii[mk];
  }
  __syncthreads();
  const float sc = 1.0f / (float)M_HALF;
  float2* Zrow = Zt + (size_t)row * M_HALF;
  const int k2base = blockIdx.x * 8;
  for (int e = tid; e < 1600; e += 256) {
    int k1 = e >> 3, k2o = e & 7;
    int j = k1 + 200 * k2o;
    int k = base + j;
    float xr = dRe[j], xi = dIm[j];
    float yr = mRe[j], yi = mIm[j];
    if (k == 0) { xi = 0.f; yi = 0.f; }  // c2r drops Im at DC & Nyquist
    float Er = 0.5f * (xr + yr);
    float Ei = 0.5f * (xi - yi);
    float Dr = 0.5f * (xr - yr);
    float Di = 0.5f * (xi + yi);
    float2 wp = Wpack[k];
    float tr = wp.x * Dr - wp.y * Di;
    float ti = wp.x * Di + wp.y * Dr;
    Zrow[k1 * 240 + k2base + k2o] = make_float2((Er - ti) * sc, (Ei + tr) * sc);
  }
}

// ---------------------------------------------------------------------------
// kernel1: 240-pt IDFT over k2 (contiguous Zt reads) + CT twiddle,
// transposed store.  G[row][n2][k1] = e^{2pi i k1 n2/48000} *
//                                     sum_k2 Zf[k1+200 k2] e^{2pi i k2 n2/240}
// Block: 8 consecutive k1 columns, one row. 25 tiles x rows.
// ---------------------------------------------------------------------------
__global__ __launch_bounds__(256) void k1_kernel(
    const float2* __restrict__ Zt, float2* __restrict__ G,
    const float2* __restrict__ Wm, const float2* __restrict__ W240) {
  __shared__ float2 LA[8 * CS1];
  __shared__ float2 LB[8 * CS1];
  const int tid = threadIdx.x;
  const int row = blockIdx.y;
  const int K0 = blockIdx.x * 8;

  // ---- contiguous load: 8 columns x 240 float2
  {
    const float2* Zrow = Zt + (size_t)row * M_HALF + (size_t)K0 * 240;
    for (int j = tid; j < 8 * 240; j += 256) {
      int col = j / 240, k2 = j - col * 240;
      LA[col * CS1 + k2] = Zrow[j];
    }
  }
  __syncthreads();
  // ---- stage <R=4,S=1,NN=240>: in p+60j -> out 4p+u, tw W240^{up}
  for (int e = tid; e < 8 * 60; e += 256) {
    int col = e & 7, p = e >> 3;
    const float2* in = LA + col * CS1;
    float2 o0, o1, o2, o3;
    bfly4i(in[p], in[p + 60], in[p + 120], in[p + 180], o0, o1, o2, o3);
    o1 = cmulf(o1, W240[p]);
    o2 = cmulf(o2, W240[2 * p]);
    o3 = cmulf(o3, W240[3 * p]);
    float2* out = LB + col * CS1 + 4 * p;
    out[0] = o0; out[1] = o1; out[2] = o2; out[3] = o3;
  }
  __syncthreads();
  // ---- stage <R=4,S=4,NN=60>: in q+4(p+15j) -> q+4(4p+u), tw W60^{up}=W240[4up]
  for (int e = tid; e < 8 * 60; e += 256) {
    int col = e & 7, t = e >> 3;
    int q = t & 3, p = t >> 2;
    const float2* in = LB + col * CS1;
    float2 o0, o1, o2, o3;
    bfly4i(in[q + 4 * p], in[q + 4 * (p + 15)], in[q + 4 * (p + 30)],
           in[q + 4 * (p + 45)], o0, o1, o2, o3);
    o1 = cmulf(o1, W240[4 * p]);
    o2 = cmulf(o2, W240[8 * p]);
    o3 = cmulf(o3, W240[12 * p]);
    float2* out = LA + col * CS1 + q;
    out[4 * (4 * p + 0)] = o0; out[4 * (4 * p + 1)] = o1;
    out[4 * (4 * p + 2)] = o2; out[4 * (4 * p + 3)] = o3;
  }
  __syncthreads();
  // ---- stage <R=15,S=16,NN=15>: in q+16j -> q+16u, no tw
  {
    float2 w15[15];
#pragma unroll
    for (int m = 0; m < 15; ++m) w15[m] = W240[16 * m];
    for (int e = tid; e < 8 * 16; e += 256) {
      int col = e & 7, q = e >> 3;
      const float2* in = LA + col * CS1 + q;
      float2 a[15];
#pragma unroll
      for (int j = 0; j < 15; ++j) a[j] = in[16 * j];
      float2* out = LB + col * CS1 + q;
#pragma unroll
      for (int u = 0; u < 15; ++u) {
        float2 acc = a[0];
#pragma unroll
        for (int j = 1; j < 15; ++j) {
          float2 w = w15[(u * j) % 15];
          acc.x += a[j].x * w.x - a[j].y * w.y;
          acc.y += a[j].x * w.y + a[j].y * w.x;
        }
        out[16 * u] = acc;
      }
    }
  }
  __syncthreads();
  // ---- CT twiddle (incremental) + transposed store G[n2*200 + k1]
  {
    const int col = tid & 7;
    const int k1 = K0 + col;
    int n2 = tid >> 3;                       // [0,32)
    float2 tw = Wm[k1 * n2];                 // max 199*31 < 48000
    const float2 twstep = Wm[32 * k1];       // max 32*199 < 48000
    float2* Grow = G + (size_t)row * M_HALF;
    const float2* in = LB + col * CS1;
    for (; n2 < 240; n2 += 32) {
      Grow[(size_t)n2 * 200 + k1] = cmulf(in[n2], tw);
      tw = cmulf(tw, twstep);
    }
  }
}

// ---------------------------------------------------------------------------
// kernel2: 200-pt IDFT over k1 (contiguous reads), scatter store to time order.
// x[n2 + 240*n1] = sum_k1 G[n2][k1] e^{2pi i k1 n1/200}
// ---------------------------------------------------------------------------
__global__ __launch_bounds__(256) void k2_kernel(
    const float2* __restrict__ G, float2* __restrict__ X,
    const float2* __restrict__ W200) {
  __shared__ float2 LA[8 * CS2];
  __shared__ float2 LB[8 * CS2];
  const int tid = threadIdx.x;
  const int row = blockIdx.y;
  const int N20 = blockIdx.x * 8;
  const float2* Grow = G + (size_t)row * M_HALF;

  for (int e = tid; e < 8 * 200; e += 256) {
    int n2o = e / 200;
    int k1 = e - n2o * 200;
    LA[n2o * CS2 + k1] = Grow[(size_t)(N20 + n2o) * 200 + k1];
  }
  __syncthreads();
  // ---- stage <R=4,S=1,NN=200>
  for (int e = tid; e < 8 * 50; e += 256) {
    int col = e & 7, p = e >> 3;
    const float2* in = LA + col * CS2;
    float2 o0, o1, o2, o3;
    bfly4i(in[p], in[p + 50], in[p + 100], in[p + 150], o0, o1, o2, o3);
    o1 = cmulf(o1, W200[p]);
    o2 = cmulf(o2, W200[2 * p]);
    o3 = cmulf(o3, W200[3 * p]);
    float2* out = LB + col * CS2 + 4 * p;
    out[0] = o0; out[1] = o1; out[2] = o2; out[3] = o3;
  }
  __syncthreads();
  // ---- stage <R=5,S=4,NN=50>
  {
    float2 w5[5];
#pragma unroll
    for (int m = 0; m < 5; ++m) w5[m] = W200[40 * m];
    for (int e = tid; e < 8 * 40; e += 256) {
      int col = e & 7, t = e >> 3;
      int q = t & 3, p = t >> 2;
      const float2* in = LB + col * CS2 + q;
      float2 a[5];
#pragma unroll
      for (int j = 0; j < 5; ++j) a[j] = in[4 * (p + 10 * j)];
      float2* out = LA + col * CS2 + q;
#pragma unroll
      for (int u = 0; u < 5; ++u) {
        float2 acc = a[0];
#pragma unroll
        for (int j = 1; j < 5; ++j) {
          float2 w = w5[(u * j) % 5];
          acc.x += a[j].x * w.x - a[j].y * w.y;
          acc.y += a[j].x * w.y + a[j].y * w.x;
        }
        acc = cmulf(acc, W200[4 * u * p]);
        out[4 * (5 * p + u)] = acc;
      }
    }
  }
  __syncthreads();
  // ---- stage <R=10,S=20,NN=10>
  {
    float2 w10[10];
#pragma unroll
    for (int m = 0; m < 10; ++m) w10[m] = W200[20 * m];
    for (int e = tid; e < 8 * 20; e += 256) {
      int col = e & 7, q = e >> 3;
      const float2* in = LA + col * CS2 + q;
      float2 a[10];
#pragma unroll
      for (int j = 0; j < 10; ++j) a[j] = in[20 * j];
      float2* out = LB + col * CS2 + q;
#pragma unroll
      for (int u = 0; u < 10; ++u) {
        float2 acc = a[0];
#pragma unroll
        for (int j = 1; j < 10; ++j) {
          float2 w = w10[(u * j) % 10];
          acc.x += a[j].x * w.x - a[j].y * w.y;
          acc.y += a[j].x * w.y + a[j].y * w.x;
        }
        out[20 * u] = acc;
      }
    }
  }
  __syncthreads();
  // ---- store: x[(N20+n2o) + 240*n1] = LB[n2o][n1]
  {
    const int n2o = tid & 7;
    float2* Xrow = X + (size_t)row * M_HALF + (N20 + n2o);
    const float2* in = LB + n2o * CS2;
    for (int n1 = tid >> 3; n1 < 200; n1 += 32)
      Xrow[240 * n1] = in[n1];
  }
}

// ------------------------------------------------- STFT: real-512 via complex-256
__global__ __launch_bounds__(256) void stft256_kernel(
    const float* __restrict__ xtime, float* __restrict__ P,
    const float2* __restrict__ W512, const float* __restrict__ hann) {
  __shared__ float2 lds[4][2][288];   // per-wave ping-pong, padded
  const int tid = threadIdx.x;
  const int wave = tid >> 6;
  const int l = tid & 63;
  const int row = blockIdx.y;
  const int frame0 = (blockIdx.x * 4 + wave) * FPW;

  float2* Abuf = lds[wave][0];
  float2* Bbuf = lds[wave][1];

  const float2* hann2 = (const float2*)hann;
  float2 hw[4];
#pragma unroll
  for (int j = 0; j < 4; ++j) hw[j] = hann2[l + 64 * j];
  float2 t1[3], t2[3], t3[3];
  {
    int p2 = l >> 2, p3 = l >> 4;
#pragma unroll
    for (int u = 1; u <= 3; ++u) {
      t1[u - 1] = W512[2 * u * l];
      t2[u - 1] = W512[8 * u * p2];
      t3[u - 1] = W512[32 * u * p3];
    }
  }

  const float2* xrow = (const float2*)xtime + (size_t)row * 48000;

  for (int fi = 0; fi < FPW; ++fi) {
    const int fr = frame0 + fi;
    const bool active = (fr < NFRAMES);
    float2 z[4];
    if (active) {
      const float2* src = xrow + fr * 128;
#pragma unroll
      for (int j = 0; j < 4; ++j) {
        float2 v = src[l + 64 * j];
        z[j] = make_float2(v.x * hw[j].x, v.y * hw[j].y);
      }
    } else {
#pragma unroll
      for (int j = 0; j < 4; ++j) z[j] = make_float2(0.f, 0.f);
    }
    float2 o0, o1, o2, o3;
    bfly4(z[0], z[1], z[2], z[3], o0, o1, o2, o3);
    o1 = cmulf(o1, t1[0]); o2 = cmulf(o2, t1[1]); o3 = cmulf(o3, t1[2]);
    Abuf[PIDX(4 * l + 0)] = o0; Abuf[PIDX(4 * l + 1)] = o1;
    Abuf[PIDX(4 * l + 2)] = o2; Abuf[PIDX(4 * l + 3)] = o3;
    WAVE_SYNC();
    {
      int q = l & 3, p = l >> 2;
      float2 a0 = Abuf[PIDX(q + 4 * p)];
      float2 a1 = Abuf[PIDX(q + 4 * (p + 16))];
      float2 a2 = Abuf[PIDX(q + 4 * (p + 32))];
      float2 a3 = Abuf[PIDX(q + 4 * (p + 48))];
      bfly4(a0, a1, a2, a3, o0, o1, o2, o3);
      o1 = cmulf(o1, t2[0]); o2 = cmulf(o2, t2[1]); o3 = cmulf(o3, t2[2]);
      int wb = q + 16 * p;
      Bbuf[PIDX(wb)] = o0; Bbuf[PIDX(wb + 4)] = o1;
      Bbuf[PIDX(wb + 8)] = o2; Bbuf[PIDX(wb + 12)] = o3;
    }
    WAVE_SYNC();
    {
      int q = l & 15, p = l >> 4;
      float2 a0 = Bbuf[PIDX(q + 16 * p)];
      float2 a1 = Bbuf[PIDX(q + 16 * (p + 4))];
      float2 a2 = Bbuf[PIDX(q + 16 * (p + 8))];
      float2 a3 = Bbuf[PIDX(q + 16 * (p + 12))];
      bfly4(a0, a1, a2, a3, o0, o1, o2, o3);
      o1 = cmulf(o1, t3[0]); o2 = cmulf(o2, t3[1]); o3 = cmulf(o3, t3[2]);
      int wb = q + 64 * p;
      Abuf[PIDX(wb)] = o0; Abuf[PIDX(wb + 16)] = o1;
      Abuf[PIDX(wb + 32)] = o2; Abuf[PIDX(wb + 48)] = o3;
    }
    WAVE_SYNC();
    {
      float2 a0 = Abuf[PIDX(l)];
      float2 a1 = Abuf[PIDX(l + 64)];
      float2 a2 = Abuf[PIDX(l + 128)];
      float2 a3 = Abuf[PIDX(l + 192)];
      bfly4(a0, a1, a2, a3, o0, o1, o2, o3);
      Bbuf[PIDX(l)] = o0; Bbuf[PIDX(l + 64)] = o1;
      Bbuf[PIDX(l + 128)] = o2; Bbuf[PIDX(l + 192)] = o3;
    }
    WAVE_SYNC();
    if (active) {
      float* Prow = P + ((size_t)row * NFRAMES + fr) * NBINS;
      for (int k = l; k <= 256; k += 64) {
        float2 Zk = Bbuf[PIDX(k & 255)];
        float2 Zm = Bbuf[PIDX((256 - k) & 255)];
        float2 E  = make_float2(0.5f * (Zk.x + Zm.x), 0.5f * (Zk.y - Zm.y));
        float2 Op = make_float2(Zk.x - Zm.x, Zk.y + Zm.y);
        float2 Od = make_float2(0.5f * Op.y, -0.5f * Op.x);
        float2 W  = W512[k];
        float2 Xb = make_float2(E.x + W.x * Od.x - W.y * Od.y,
                                E.y + W.x * Od.y + W.y * Od.x);
        Prow[k] = Xb.x * Xb.x + Xb.y * Xb.y;
      }
    }
    WAVE_SYNC();
  }
}

// ---------------------------------- EDR phase A: per-group partial sums
__global__ __launch_bounds__(256) void edrA_kernel(const float* __restrict__ P,
                                                   float* __restrict__ part) {
  const int r = blockIdx.x;
  const int g = blockIdx.y;
  const float* Pr = P + (size_t)r * (NFRAMES * NBINS);
  for (int bin = threadIdx.x; bin < NBINS; bin += 256) {
    float s = 0.f;
    const int m0 = g * GLEN;
    for (int m = m0; m < m0 + GLEN; ++m) s += Pr[m * NBINS + bin];
    part[((size_t)r * NG + g) * NBINS + bin] = s;
  }
}

// ------------------- EDR phase B: suffix offsets + in-group chain + reduction
__global__ __launch_bounds__(256) void edrB_kernel(const float* __restrict__ P,
                                                   const float* __restrict__ part,
                                                   double* __restrict__ accum, int c) {
  const int b = blockIdx.x;
  const int g = blockIdx.y;
  const float* Pt = P + (size_t)b * (NFRAMES * NBINS);
  const float* Pa = P + (size_t)(b + c) * (NFRAMES * NBINS);
  const float* qt = part + (size_t)b * NG * NBINS;
  const float* qa = part + (size_t)(b + c) * NG * NBINS;
  float sn = 0.f, sd = 0.f;
  for (int bin = threadIdx.x; bin < NBINS; bin += 256) {
    float ct = 0.f, ca = 0.f;
    for (int g2 = g + 1; g2 < NG; ++g2) {
      ct += qt[g2 * NBINS + bin];
      ca += qa[g2 * NBINS + bin];
    }
    const int m0 = g * GLEN;
    for (int m = m0 + GLEN - 1; m >= m0; --m) {
      ct += Pt[m * NBINS + bin];
      ca += Pa[m * NBINS + bin];
      float lt = 10.f * log10f(ct);
      float la = 10.f * log10f(ca);
      sn += fabsf(lt - la);
      sd += fabsf(lt);
    }
  }
#pragma unroll
  for (int off = 32; off > 0; off >>= 1) {
    sn += __shfl_down(sn, off, 64);
    sd += __shfl_down(sd, off, 64);
  }
  __shared__ float wsn[4], wsd[4];
  const int wave = threadIdx.x >> 6;
  if ((threadIdx.x & 63) == 0) { wsn[wave] = sn; wsd[wave] = sd; }
  __syncthreads();
  if (threadIdx.x == 0) {
    float tn = 0.f, td = 0.f;
#pragma unroll
    for (int w = 0; w < 4; ++w) { tn += wsn[w]; td += wsd[w]; }
    int slot = (blockIdx.x * NG + blockIdx.y) & 63;
    atomicAdd(&accum[slot], (double)tn);
    atomicAdd(&accum[64 + slot], (double)td);
  }
}

__global__ void final_kernel(const double* __restrict__ accum, float* __restrict__ out) {
  double n = 0.0, d = 0.0;
  for (int i = 0; i < 64; ++i) { n += accum[i]; d += accum[64 + i]; }
  out[0] = (float)(n / d);
}

// ---------------------------------------------------------------- launcher
extern "C" void kernel_launch(void* const* d_in, const int* in_sizes, int n_in,
                              void* d_out, int out_size, void* d_ws, size_t ws_size,
                              hipStream_t stream) {
  const float* tre = (const float*)d_in[0];
  const float* tim = (const float*)d_in[1];
  const float* are = (const float*)d_in[2];
  const float* aim = (const float*)d_in[3];
  float* out = (float*)d_out;

  char* base = (char*)d_ws;
  size_t off = 0;
  auto take = [&](size_t bytes) -> char* {
    char* p = base + off;
    off += (bytes + 255) & ~(size_t)255;
    return p;
  };
  float2* Wm    = (float2*)take((size_t)M_HALF * sizeof(float2));
  float2* Wpack = (float2*)take((size_t)M_HALF * sizeof(float2));
  float2* W512  = (float2*)take(512 * sizeof(float2));
  float*  hann  = (float*)take(512 * sizeof(float));
  float2* W240  = (float2*)take(240 * sizeof(float2));
  float2* W200  = (float2*)take(200 * sizeof(float2));
  double* accum = (double*)take(128 * sizeof(double));
  size_t fixed = off;

  // per-batch-unit (2 rows): buf1 = Zt then X (time), buf2 = G then P, part
  const size_t perA    = (size_t)2 * M_HALF * sizeof(float2);         // 768000
  const size_t perP    = (size_t)2 * NFRAMES * NBINS * sizeof(float); // 768944
  const size_t perPart = (size_t)2 * NG * NBINS * sizeof(float);      // 22616
  int c = 1;
  const int cands[8] = {128, 64, 32, 16, 8, 4, 2, 1};
  for (int ci = 0; ci < 8; ++ci) {
    size_t need = fixed + ((cands[ci] * perA + 255) & ~(size_t)255)
                        + ((cands[ci] * perP + 255) & ~(size_t)255)
                        + ((cands[ci] * perPart + 255) & ~(size_t)255);
    if (need <= ws_size) { c = cands[ci]; break; }
  }
  float2* buf1 = (float2*)take((size_t)c * perA);
  char*   BP   = take((size_t)c * perP);
  float*  part = (float*)take((size_t)c * perPart);
  float2* Zt = buf1;          // pass0 out / k1 in
  float2* X  = buf1;          // k2 out (Zt dead after k1... reused after k2 reads G)
  float2* G  = (float2*)BP;   // k1 out / k2 in
  float*  P  = (float*)BP;    // stft out (aliases G; G dead after k2)

  setup_kernel<<<(M_HALF + 255) / 256, 256, 0, stream>>>(Wm, Wpack, W512, hann,
                                                         W240, W200);
  hipMemsetAsync(accum, 0, 128 * sizeof(double), stream);

  for (int b0 = 0; b0 < BATCH; b0 += c) {
    int rows = 2 * c;
    packT_kernel<<<dim3(30, rows), 256, 0, stream>>>(tre, tim, are, aim, Zt,
                                                     Wpack, b0, c);
    k1_kernel<<<dim3(25, rows), 256, 0, stream>>>(Zt, G, Wm, W240);
    k2_kernel<<<dim3(30, rows), 256, 0, stream>>>(G, X, W200);
    {
      dim3 grid((NFRAMES + 4 * FPW - 1) / (4 * FPW), rows);
      stft256_kernel<<<grid, 256, 0, stream>>>((const float*)X, P, W512, hann);
    }
    edrA_kernel<<<dim3(rows, NG), 256, 0, stream>>>(P, part);
    edrB_kernel<<<dim3(c, NG), 256, 0, stream>>>(P, part, accum, c);
  }
  final_kernel<<<1, 1, 0, stream>>>(accum, out);
}

// Round 5
// 415.864 us; speedup vs baseline: 1.5084x; 1.0774x over previous
//
#include <hip/hip_runtime.h>
#include <math.h>

#define BATCH   128
#define NFREQ   96000      // input row length (freq pts); irfft length
#define M_HALF  48000      // complex IDFT length
#define NFRAMES 374
#define NBINS   257
#define PPITCH  258        // padded row pitch for P / part (float2 alignment)
#define NG      11         // frame groups for segmented reverse cumsum
#define GLEN    34         // 11 * 34 = 374 exactly
#define FPW     4          // frames per wave in stft kernel

#define CS1 246            // LDS column stride, kernel1 (240-pt), even
#define CS2 206            // LDS column stride, kernel2 (200-pt), even

#define PI_D 3.14159265358979323846

// wave-local LDS sync (LDS region wave-private; 64 lanes lockstep)
#define WAVE_SYNC() __asm__ volatile("s_waitcnt lgkmcnt(0)" ::: "memory")

__device__ __forceinline__ float2 cmulf(float2 a, float2 b) {
  return make_float2(a.x * b.x - a.y * b.y, a.x * b.y + a.y * b.x);
}

// forward radix-4 butterfly (w4 = -i)
__device__ __forceinline__ void bfly4(float2 z0, float2 z1, float2 z2, float2 z3,
                                      float2& o0, float2& o1, float2& o2, float2& o3) {
  float2 e0 = make_float2(z0.x + z2.x, z0.y + z2.y);
  float2 e1 = make_float2(z0.x - z2.x, z0.y - z2.y);
  float2 e2 = make_float2(z1.x + z3.x, z1.y + z3.y);
  float2 e3 = make_float2(z1.x - z3.x, z1.y - z3.y);
  o0 = make_float2(e0.x + e2.x, e0.y + e2.y);
  o2 = make_float2(e0.x - e2.x, e0.y - e2.y);
  o1 = make_float2(e1.x + e3.y, e1.y - e3.x);   // e1 - i*e3
  o3 = make_float2(e1.x - e3.y, e1.y + e3.x);   // e1 + i*e3
}

// inverse radix-4 butterfly (w4 = +i)
__device__ __forceinline__ void bfly4i(float2 z0, float2 z1, float2 z2, float2 z3,
                                       float2& o0, float2& o1, float2& o2, float2& o3) {
  float2 e0 = make_float2(z0.x + z2.x, z0.y + z2.y);
  float2 e1 = make_float2(z0.x - z2.x, z0.y - z2.y);
  float2 e2 = make_float2(z1.x + z3.x, z1.y + z3.y);
  float2 e3 = make_float2(z1.x - z3.x, z1.y - z3.y);
  o0 = make_float2(e0.x + e2.x, e0.y + e2.y);
  o2 = make_float2(e0.x - e2.x, e0.y - e2.y);
  o1 = make_float2(e1.x - e3.y, e1.y + e3.x);   // e1 + i*e3
  o3 = make_float2(e1.x + e3.y, e1.y - e3.x);   // e1 - i*e3
}

#define PIDX(i) ((i) + ((i) >> 3))

// ---------------------------------------------------------------- tables
__global__ void setup_kernel(float2* __restrict__ Wm, float2* __restrict__ Wpack,
                             float2* __restrict__ W512, float* __restrict__ hann,
                             float2* __restrict__ W240, float2* __restrict__ W200) {
  int i = blockIdx.x * blockDim.x + threadIdx.x;
  if (i < M_HALF) {
    double th = 2.0 * PI_D * (double)i / (double)M_HALF;   // e^{+2pi i k/48000}
    double s, c; sincos(th, &s, &c);
    Wm[i] = make_float2((float)c, (float)s);
    double th2 = PI_D * (double)i / (double)M_HALF;        // e^{+i pi k/48000}
    double s2, c2; sincos(th2, &s2, &c2);
    Wpack[i] = make_float2((float)c2, (float)s2);
  }
  if (i < 512) {
    double th = -2.0 * PI_D * (double)i / 512.0;           // forward FFT
    double s, c; sincos(th, &s, &c);
    W512[i] = make_float2((float)c, (float)s);
    hann[i] = (float)(0.5 * (1.0 - cos(2.0 * PI_D * (double)i / 512.0)));
  }
  if (i < 240) {
    double th = 2.0 * PI_D * (double)i / 240.0;
    double s, c; sincos(th, &s, &c);
    W240[i] = make_float2((float)c, (float)s);
  }
  if (i < 200) {
    double th = 2.0 * PI_D * (double)i / 200.0;
    double s, c; sincos(th, &s, &c);
    W200[i] = make_float2((float)c, (float)s);
  }
}

// ---------------------------------------------------------------------------
// pass0: fused pack + transpose, fully float4.
// Zf[k] = (E + i*Wpack[k]*D)/M from X[k], X[48000-k];
// store k1-major: Zt[row][k1*240 + k2], k = k1 + 200*k2.
// Block: contiguous k span of 1600 (= 8 k2 x 200 k1).
//   direct span  : [base, base+1600)            (float4 loads)
//   mirror window: [M-base-1600, M-base+4)      (aligned float4; index-reversed)
// ---------------------------------------------------------------------------
__global__ __launch_bounds__(256) void packT_kernel(
    const float* __restrict__ tre, const float* __restrict__ tim,
    const float* __restrict__ are, const float* __restrict__ aim,
    float2* __restrict__ Zt, const float2* __restrict__ Wpack, int b0, int c) {
  __shared__ float4 dRe4[400], dIm4[400], mRe4[401], mIm4[401];
  float* dRe = (float*)dRe4;   // dRe[j]       = rr[base + j],        j in [0,1600)
  float* dIm = (float*)dIm4;
  float* mRe = (float*)mRe4;   // mRe[i]       = rr[M-base-1600 + i], i in [0,1604)
  float* mIm = (float*)mIm4;   //  -> rr[M-base-j] = mRe[1600 - j]
  const int tid = threadIdx.x;
  const int row = blockIdx.y;
  const int base = blockIdx.x * 1600;         // k in [base, base+1600)
  const int moff = M_HALF - base - 1600;      // >= 0; 16B aligned
  const int isA = row >= c;
  const int b = b0 + (isA ? row - c : row);
  const float* rr = (isA ? are : tre) + (size_t)b * NFREQ;
  const float* ii = (isA ? aim : tim) + (size_t)b * NFREQ;
  {
    const float4* rd = (const float4*)(rr + base);
    const float4* id = (const float4*)(ii + base);
    for (int v = tid; v < 400; v += 256) { dRe4[v] = rd[v]; dIm4[v] = id[v]; }
    const float4* rm = (const float4*)(rr + moff);
    const float4* im = (const float4*)(ii + moff);
    for (int v = tid; v < 401; v += 256) { mRe4[v] = rm[v]; mIm4[v] = im[v]; }
  }
  __syncthreads();
  const float sc = 1.0f / (float)M_HALF;
  float2* Zrow = Zt + (size_t)row * M_HALF;
  const int k2base = blockIdx.x * 8;
  for (int e = tid; e < 800; e += 256) {
    int k1 = e >> 2, k2p = e & 3;             // k2o = 2*k2p, 2*k2p+1
    float2 z[2];
#pragma unroll
    for (int h = 0; h < 2; ++h) {
      int j = k1 + 200 * (2 * k2p + h);
      int k = base + j;
      float xr = dRe[j], xi = dIm[j];
      float yr = mRe[1600 - j], yi = mIm[1600 - j];
      if (k == 0) { xi = 0.f; yi = 0.f; }     // c2r drops Im at DC & Nyquist
      float Er = 0.5f * (xr + yr);
      float Ei = 0.5f * (xi - yi);
      float Dr = 0.5f * (xr - yr);
      float Di = 0.5f * (xi + yi);
      float2 wp = Wpack[k];
      float tr = wp.x * Dr - wp.y * Di;
      float ti = wp.x * Di + wp.y * Dr;
      z[h] = make_float2((Er - ti) * sc, (Ei + tr) * sc);
    }
    ((float4*)Zrow)[k1 * 120 + (k2base >> 1) + k2p] =
        make_float4(z[0].x, z[0].y, z[1].x, z[1].y);
  }
}

// ---------------------------------------------------------------------------
// kernel1: 240-pt IDFT over k2 (contiguous float4 Zt reads) + CT twiddle,
// float4 transposed store.  G[row][n2*200+k1] = Wm[k1*n2] *
//                             sum_k2 Zf[k1+200 k2] e^{2pi i k2 n2/240}
// Block: 8 consecutive k1 columns, one row. 25 tiles x rows.
// ---------------------------------------------------------------------------
__global__ __launch_bounds__(256) void k1_kernel(
    const float2* __restrict__ Zt, float2* __restrict__ G,
    const float2* __restrict__ Wm, const float2* __restrict__ W240) {
  __shared__ float2 LA[8 * CS1];
  __shared__ float2 LB[8 * CS1];
  const int tid = threadIdx.x;
  const int row = blockIdx.y;
  const int K0 = blockIdx.x * 8;

  // ---- contiguous float4 load: 8 columns x 240 float2 = 960 float4
  {
    const float4* Zrow4 = (const float4*)(Zt + (size_t)row * M_HALF + (size_t)K0 * 240);
    for (int v = tid; v < 960; v += 256) {
      int col = v / 120;
      int k2 = 2 * (v - col * 120);
      *((float4*)(LA + col * CS1 + k2)) = Zrow4[v];
    }
  }
  __syncthreads();
  // ---- stage <R=4,S=1,NN=240>: in p+60j -> out 4p+u, tw W240^{up}
  for (int e = tid; e < 8 * 60; e += 256) {
    int col = e & 7, p = e >> 3;
    const float2* in = LA + col * CS1;
    float2 o0, o1, o2, o3;
    bfly4i(in[p], in[p + 60], in[p + 120], in[p + 180], o0, o1, o2, o3);
    o1 = cmulf(o1, W240[p]);
    o2 = cmulf(o2, W240[2 * p]);
    o3 = cmulf(o3, W240[3 * p]);
    float2* out = LB + col * CS1 + 4 * p;
    out[0] = o0; out[1] = o1; out[2] = o2; out[3] = o3;
  }
  __syncthreads();
  // ---- stage <R=4,S=4,NN=60>: in q+4(p+15j) -> q+4(4p+u), tw W60^{up}=W240[4up]
  for (int e = tid; e < 8 * 60; e += 256) {
    int col = e & 7, t = e >> 3;
    int q = t & 3, p = t >> 2;
    const float2* in = LB + col * CS1;
    float2 o0, o1, o2, o3;
    bfly4i(in[q + 4 * p], in[q + 4 * (p + 15)], in[q + 4 * (p + 30)],
           in[q + 4 * (p + 45)], o0, o1, o2, o3);
    o1 = cmulf(o1, W240[4 * p]);
    o2 = cmulf(o2, W240[8 * p]);
    o3 = cmulf(o3, W240[12 * p]);
    float2* out = LA + col * CS1 + q;
    out[4 * (4 * p + 0)] = o0; out[4 * (4 * p + 1)] = o1;
    out[4 * (4 * p + 2)] = o2; out[4 * (4 * p + 3)] = o3;
  }
  __syncthreads();
  // ---- stage <R=15,S=16,NN=15>: in q+16j -> q+16u, no tw
  {
    float2 w15[15];
#pragma unroll
    for (int m = 0; m < 15; ++m) w15[m] = W240[16 * m];
    for (int e = tid; e < 8 * 16; e += 256) {
      int col = e & 7, q = e >> 3;
      const float2* in = LA + col * CS1 + q;
      float2 a[15];
#pragma unroll
      for (int j = 0; j < 15; ++j) a[j] = in[16 * j];
      float2* out = LB + col * CS1 + q;
#pragma unroll
      for (int u = 0; u < 15; ++u) {
        float2 acc = a[0];
#pragma unroll
        for (int j = 1; j < 15; ++j) {
          float2 w = w15[(u * j) % 15];
          acc.x += a[j].x * w.x - a[j].y * w.y;
          acc.y += a[j].x * w.y + a[j].y * w.x;
        }
        out[16 * u] = acc;
      }
    }
  }
  __syncthreads();
  // ---- CT twiddle (incremental, per col-pair) + float4 store G[n2*200 + k1]
  {
    const int cp = tid & 3;                  // col pair -> k1 = K0+2cp, +1
    const int k1a = K0 + 2 * cp, k1b = k1a + 1;
    const int n2_0 = tid >> 2;               // [0,64)
    float2 twa = Wm[k1a * n2_0];             // <= 198*63 < 48000
    float2 twb = Wm[k1b * n2_0];             // <= 199*63 < 48000
    const float2 sta = Wm[64 * k1a];         // <= 64*198 < 48000
    const float2 stb = Wm[64 * k1b];
    float4* Grow4 = (float4*)(G + (size_t)row * M_HALF);
    const float2* ina = LB + (2 * cp) * CS1;
    const float2* inb = LB + (2 * cp + 1) * CS1;
    for (int n2 = n2_0; n2 < 240; n2 += 64) {
      float2 va = cmulf(ina[n2], twa);
      float2 vb = cmulf(inb[n2], twb);
      Grow4[n2 * 100 + (K0 >> 1) + cp] = make_float4(va.x, va.y, vb.x, vb.y);
      twa = cmulf(twa, sta);
      twb = cmulf(twb, stb);
    }
  }
}

// ---------------------------------------------------------------------------
// kernel2: 200-pt IDFT over k1 (contiguous float4 reads), float4 scatter store.
// x[n2 + 240*n1] = sum_k1 G[n2][k1] e^{2pi i k1 n1/200}
// ---------------------------------------------------------------------------
__global__ __launch_bounds__(256) void k2_kernel(
    const float2* __restrict__ G, float2* __restrict__ X,
    const float2* __restrict__ W200) {
  __shared__ float2 LA[8 * CS2];
  __shared__ float2 LB[8 * CS2];
  const int tid = threadIdx.x;
  const int row = blockIdx.y;
  const int N20 = blockIdx.x * 8;

  {
    const float4* Grow4 = (const float4*)(G + (size_t)row * M_HALF + (size_t)N20 * 200);
    for (int v = tid; v < 800; v += 256) {
      int n2o = v / 100;
      int k1 = 2 * (v - n2o * 100);
      *((float4*)(LA + n2o * CS2 + k1)) = Grow4[v];
    }
  }
  __syncthreads();
  // ---- stage <R=4,S=1,NN=200>
  for (int e = tid; e < 8 * 50; e += 256) {
    int col = e & 7, p = e >> 3;
    const float2* in = LA + col * CS2;
    float2 o0, o1, o2, o3;
    bfly4i(in[p], in[p + 50], in[p + 100], in[p + 150], o0, o1, o2, o3);
    o1 = cmulf(o1, W200[p]);
    o2 = cmulf(o2, W200[2 * p]);
    o3 = cmulf(o3, W200[3 * p]);
    float2* out = LB + col * CS2 + 4 * p;
    out[0] = o0; out[1] = o1; out[2] = o2; out[3] = o3;
  }
  __syncthreads();
  // ---- stage <R=5,S=4,NN=50>
  {
    float2 w5[5];
#pragma unroll
    for (int m = 0; m < 5; ++m) w5[m] = W200[40 * m];
    for (int e = tid; e < 8 * 40; e += 256) {
      int col = e & 7, t = e >> 3;
      int q = t & 3, p = t >> 2;
      const float2* in = LB + col * CS2 + q;
      float2 a[5];
#pragma unroll
      for (int j = 0; j < 5; ++j) a[j] = in[4 * (p + 10 * j)];
      float2* out = LA + col * CS2 + q;
#pragma unroll
      for (int u = 0; u < 5; ++u) {
        float2 acc = a[0];
#pragma unroll
        for (int j = 1; j < 5; ++j) {
          float2 w = w5[(u * j) % 5];
          acc.x += a[j].x * w.x - a[j].y * w.y;
          acc.y += a[j].x * w.y + a[j].y * w.x;
        }
        acc = cmulf(acc, W200[4 * u * p]);
        out[4 * (5 * p + u)] = acc;
      }
    }
  }
  __syncthreads();
  // ---- stage <R=10,S=20,NN=10>
  {
    float2 w10[10];
#pragma unroll
    for (int m = 0; m < 10; ++m) w10[m] = W200[20 * m];
    for (int e = tid; e < 8 * 20; e += 256) {
      int col = e & 7, q = e >> 3;
      const float2* in = LA + col * CS2 + q;
      float2 a[10];
#pragma unroll
      for (int j = 0; j < 10; ++j) a[j] = in[20 * j];
      float2* out = LB + col * CS2 + q;
#pragma unroll
      for (int u = 0; u < 10; ++u) {
        float2 acc = a[0];
#pragma unroll
        for (int j = 1; j < 10; ++j) {
          float2 w = w10[(u * j) % 10];
          acc.x += a[j].x * w.x - a[j].y * w.y;
          acc.y += a[j].x * w.y + a[j].y * w.x;
        }
        out[20 * u] = acc;
      }
    }
  }
  __syncthreads();
  // ---- float4 store: x[(N20 + 2np + h) + 240*n1] for h=0,1
  {
    const int np = tid & 3;                  // n2o pair
    const int n1_0 = tid >> 2;               // [0,64)
    const float2* in0 = LB + (2 * np) * CS2;
    const float2* in1 = LB + (2 * np + 1) * CS2;
    float4* Xrow4 = (float4*)(X + (size_t)row * M_HALF);
    for (int n1 = n1_0; n1 < 200; n1 += 64) {
      float2 v0 = in0[n1], v1 = in1[n1];
      Xrow4[(N20 >> 1) + np + 120 * n1] = make_float4(v0.x, v0.y, v1.x, v1.y);
    }
  }
}

// ------------------------------------------------- STFT: real-512 via complex-256
// + fused per-group power accumulation into `part` (atomicAdd at group/wave ends)
__global__ __launch_bounds__(256) void stft256_kernel(
    const float* __restrict__ xtime, float* __restrict__ P,
    float* __restrict__ part,
    const float2* __restrict__ W512, const float* __restrict__ hann) {
  __shared__ float2 lds[4][2][288];   // per-wave ping-pong, padded
  const int tid = threadIdx.x;
  const int wave = tid >> 6;
  const int l = tid & 63;
  const int row = blockIdx.y;
  const int frame0 = (blockIdx.x * 4 + wave) * FPW;

  float2* Abuf = lds[wave][0];
  float2* Bbuf = lds[wave][1];

  const float4 hh0 = ((const float4*)hann)[l];        // floats 4l..4l+3
  const float4 hh1 = ((const float4*)hann)[l + 64];   // floats 256+4l..+3
  float2 t1[3], t2[3], t3[3];
  {
    int p2 = l >> 2, p3 = l >> 4;
#pragma unroll
    for (int u = 1; u <= 3; ++u) {
      t1[u - 1] = W512[2 * u * l];
      t2[u - 1] = W512[8 * u * p2];
      t3[u - 1] = W512[32 * u * p3];
    }
  }

  const float2* xrow = (const float2*)xtime + (size_t)row * 48000;
  float acc[5] = {0.f, 0.f, 0.f, 0.f, 0.f};

  for (int fi = 0; fi < FPW; ++fi) {
    const int fr = frame0 + fi;
    if (fr >= NFRAMES) break;
    // ---- stage global->LDS (float4, windowed), linear layout in Bbuf
    {
      const float4* src4 = (const float4*)(xrow + fr * 128);
      float4 v0 = src4[l];
      float4 v1 = src4[l + 64];
      v0.x *= hh0.x; v0.y *= hh0.y; v0.z *= hh0.z; v0.w *= hh0.w;
      v1.x *= hh1.x; v1.y *= hh1.y; v1.z *= hh1.z; v1.w *= hh1.w;
      ((float4*)Bbuf)[l] = v0;        // float2 slots 2l, 2l+1
      ((float4*)Bbuf)[l + 64] = v1;   // float2 slots 128+2l, 128+2l+1
    }
    WAVE_SYNC();
    float2 o0, o1, o2, o3;
    // stage 1 (S=1): read linear Bbuf, write PIDX Abuf
    {
      float2 z0 = Bbuf[l], z1 = Bbuf[l + 64], z2 = Bbuf[l + 128], z3 = Bbuf[l + 192];
      bfly4(z0, z1, z2, z3, o0, o1, o2, o3);
      o1 = cmulf(o1, t1[0]); o2 = cmulf(o2, t1[1]); o3 = cmulf(o3, t1[2]);
      Abuf[PIDX(4 * l + 0)] = o0; Abuf[PIDX(4 * l + 1)] = o1;
      Abuf[PIDX(4 * l + 2)] = o2; Abuf[PIDX(4 * l + 3)] = o3;
    }
    WAVE_SYNC();
    {
      int q = l & 3, p = l >> 2;
      float2 a0 = Abuf[PIDX(q + 4 * p)];
      float2 a1 = Abuf[PIDX(q + 4 * (p + 16))];
      float2 a2 = Abuf[PIDX(q + 4 * (p + 32))];
      float2 a3 = Abuf[PIDX(q + 4 * (p + 48))];
      bfly4(a0, a1, a2, a3, o0, o1, o2, o3);
      o1 = cmulf(o1, t2[0]); o2 = cmulf(o2, t2[1]); o3 = cmulf(o3, t2[2]);
      int wb = q + 16 * p;
      Bbuf[PIDX(wb)] = o0; Bbuf[PIDX(wb + 4)] = o1;
      Bbuf[PIDX(wb + 8)] = o2; Bbuf[PIDX(wb + 12)] = o3;
    }
    WAVE_SYNC();
    {
      int q = l & 15, p = l >> 4;
      float2 a0 = Bbuf[PIDX(q + 16 * p)];
      float2 a1 = Bbuf[PIDX(q + 16 * (p + 4))];
      float2 a2 = Bbuf[PIDX(q + 16 * (p + 8))];
      float2 a3 = Bbuf[PIDX(q + 16 * (p + 12))];
      bfly4(a0, a1, a2, a3, o0, o1, o2, o3);
      o1 = cmulf(o1, t3[0]); o2 = cmulf(o2, t3[1]); o3 = cmulf(o3, t3[2]);
      int wb = q + 64 * p;
      Abuf[PIDX(wb)] = o0; Abuf[PIDX(wb + 16)] = o1;
      Abuf[PIDX(wb + 32)] = o2; Abuf[PIDX(wb + 48)] = o3;
    }
    WAVE_SYNC();
    {
      float2 a0 = Abuf[PIDX(l)];
      float2 a1 = Abuf[PIDX(l + 64)];
      float2 a2 = Abuf[PIDX(l + 128)];
      float2 a3 = Abuf[PIDX(l + 192)];
      bfly4(a0, a1, a2, a3, o0, o1, o2, o3);
      Bbuf[PIDX(l)] = o0; Bbuf[PIDX(l + 64)] = o1;
      Bbuf[PIDX(l + 128)] = o2; Bbuf[PIDX(l + 192)] = o3;
    }
    WAVE_SYNC();
    // unpack real-FFT bins + power + group accumulation
    {
      float* Prow = P + ((size_t)row * NFRAMES + fr) * PPITCH;
      int j = 0;
      for (int k = l; k <= 256; k += 64, ++j) {
        float2 Zk = Bbuf[PIDX(k & 255)];
        float2 Zm = Bbuf[PIDX((256 - k) & 255)];
        float2 E  = make_float2(0.5f * (Zk.x + Zm.x), 0.5f * (Zk.y - Zm.y));
        float2 Op = make_float2(Zk.x - Zm.x, Zk.y + Zm.y);
        float2 Od = make_float2(0.5f * Op.y, -0.5f * Op.x);
        float2 W  = W512[k];
        float2 Xb = make_float2(E.x + W.x * Od.x - W.y * Od.y,
                                E.y + W.x * Od.y + W.y * Od.x);
        float pwr = Xb.x * Xb.x + Xb.y * Xb.y;
        Prow[k] = pwr;
        acc[j] += pwr;
      }
      bool flush = (((fr + 1) % GLEN) == 0) || (fi == FPW - 1) || (fr == NFRAMES - 1);
      if (flush) {
        int g = fr / GLEN;
        float* prow = part + ((size_t)row * NG + g) * PPITCH;
        int j2 = 0;
        for (int k = l; k <= 256; k += 64, ++j2) {
          atomicAdd(&prow[k], acc[j2]);
          acc[j2] = 0.f;
        }
      }
    }
    WAVE_SYNC();
  }
}

// ------------------- EDR: suffix offsets + in-group chain + reduction (float2)
__global__ __launch_bounds__(192) void edrB_kernel(const float* __restrict__ P,
                                                   const float* __restrict__ part,
                                                   double* __restrict__ accum, int c) {
  const int b = blockIdx.x;
  const int g = blockIdx.y;
  const int tid = threadIdx.x;
  const float* Pt = P + (size_t)b * (NFRAMES * PPITCH);
  const float* Pa = P + (size_t)(b + c) * (NFRAMES * PPITCH);
  const float* qt = part + (size_t)b * NG * PPITCH;
  const float* qa = part + (size_t)(b + c) * NG * PPITCH;
  float sn = 0.f, sd = 0.f;
  if (tid < 128) {
    const int bin = 2 * tid;
    float2 ct = make_float2(0.f, 0.f), ca = make_float2(0.f, 0.f);
    for (int g2 = g + 1; g2 < NG; ++g2) {
      float2 vt = *(const float2*)(qt + g2 * PPITCH + bin);
      float2 va = *(const float2*)(qa + g2 * PPITCH + bin);
      ct.x += vt.x; ct.y += vt.y; ca.x += va.x; ca.y += va.y;
    }
    const int m0 = g * GLEN;
    for (int m = m0 + GLEN - 1; m >= m0; --m) {
      float2 vt = *(const float2*)(Pt + m * PPITCH + bin);
      float2 va = *(const float2*)(Pa + m * PPITCH + bin);
      ct.x += vt.x; ct.y += vt.y; ca.x += va.x; ca.y += va.y;
      float lt0 = 10.f * log10f(ct.x), la0 = 10.f * log10f(ca.x);
      float lt1 = 10.f * log10f(ct.y), la1 = 10.f * log10f(ca.y);
      sn += fabsf(lt0 - la0) + fabsf(lt1 - la1);
      sd += fabsf(lt0) + fabsf(lt1);
    }
  } else if (tid == 128) {
    const int bin = 256;
    float ct = 0.f, ca = 0.f;
    for (int g2 = g + 1; g2 < NG; ++g2) {
      ct += qt[g2 * PPITCH + bin];
      ca += qa[g2 * PPITCH + bin];
    }
    const int m0 = g * GLEN;
    for (int m = m0 + GLEN - 1; m >= m0; --m) {
      ct += Pt[m * PPITCH + bin];
      ca += Pa[m * PPITCH + bin];
      float lt = 10.f * log10f(ct), la = 10.f * log10f(ca);
      sn += fabsf(lt - la);
      sd += fabsf(lt);
    }
  }
#pragma unroll
  for (int off = 32; off > 0; off >>= 1) {
    sn += __shfl_down(sn, off, 64);
    sd += __shfl_down(sd, off, 64);
  }
  __shared__ float wsn[3], wsd[3];
  const int wave = tid >> 6;
  if ((tid & 63) == 0) { wsn[wave] = sn; wsd[wave] = sd; }
  __syncthreads();
  if (tid == 0) {
    float tn = 0.f, td = 0.f;
#pragma unroll
    for (int w = 0; w < 3; ++w) { tn += wsn[w]; td += wsd[w]; }
    int slot = (blockIdx.x * NG + blockIdx.y) & 63;
    atomicAdd(&accum[slot], (double)tn);
    atomicAdd(&accum[64 + slot], (double)td);
  }
}

__global__ void final_kernel(const double* __restrict__ accum, float* __restrict__ out) {
  double n = 0.0, d = 0.0;
  for (int i = 0; i < 64; ++i) { n += accum[i]; d += accum[64 + i]; }
  out[0] = (float)(n / d);
}

// ---------------------------------------------------------------- launcher
extern "C" void kernel_launch(void* const* d_in, const int* in_sizes, int n_in,
                              void* d_out, int out_size, void* d_ws, size_t ws_size,
                              hipStream_t stream) {
  const float* tre = (const float*)d_in[0];
  const float* tim = (const float*)d_in[1];
  const float* are = (const float*)d_in[2];
  const float* aim = (const float*)d_in[3];
  float* out = (float*)d_out;

  char* base = (char*)d_ws;
  size_t off = 0;
  auto take = [&](size_t bytes) -> char* {
    char* p = base + off;
    off += (bytes + 255) & ~(size_t)255;
    return p;
  };
  float2* Wm    = (float2*)take((size_t)M_HALF * sizeof(float2));
  float2* Wpack = (float2*)take((size_t)M_HALF * sizeof(float2));
  float2* W512  = (float2*)take(512 * sizeof(float2));
  float*  hann  = (float*)take(512 * sizeof(float));
  float2* W240  = (float2*)take(240 * sizeof(float2));
  float2* W200  = (float2*)take(200 * sizeof(float2));
  double* accum = (double*)take(128 * sizeof(double));
  size_t fixed = off;

  // per-batch-unit (2 rows): buf1 = Zt then X (time), buf2 = G then P, part
  const size_t perA    = (size_t)2 * M_HALF * sizeof(float2);           // 768000
  const size_t perP    = (size_t)2 * NFRAMES * PPITCH * sizeof(float);  // 771936
  const size_t perPart = (size_t)2 * NG * PPITCH * sizeof(float);       // 22704
  int c = 1;
  const int cands[8] = {128, 64, 32, 16, 8, 4, 2, 1};
  for (int ci = 0; ci < 8; ++ci) {
    size_t need = fixed + ((cands[ci] * perA + 255) & ~(size_t)255)
                        + ((cands[ci] * perP + 255) & ~(size_t)255)
                        + ((cands[ci] * perPart + 255) & ~(size_t)255);
    if (need <= ws_size) { c = cands[ci]; break; }
  }
  float2* buf1 = (float2*)take((size_t)c * perA);
  char*   BP   = take((size_t)c * perP);
  float*  part = (float*)take((size_t)c * perPart);
  float2* Zt = buf1;          // pass0 out / k1 in
  float2* X  = buf1;          // k2 out (Zt dead after k1)
  float2* G  = (float2*)BP;   // k1 out / k2 in
  float*  P  = (float*)BP;    // stft out (aliases G; G dead after k2)

  setup_kernel<<<(M_HALF + 255) / 256, 256, 0, stream>>>(Wm, Wpack, W512, hann,
                                                         W240, W200);
  hipMemsetAsync(accum, 0, 128 * sizeof(double), stream);

  for (int b0 = 0; b0 < BATCH; b0 += c) {
    int rows = 2 * c;
    hipMemsetAsync(part, 0, (size_t)c * perPart, stream);
    packT_kernel<<<dim3(30, rows), 256, 0, stream>>>(tre, tim, are, aim, Zt,
                                                     Wpack, b0, c);
    k1_kernel<<<dim3(25, rows), 256, 0, stream>>>(Zt, G, Wm, W240);
    k2_kernel<<<dim3(30, rows), 256, 0, stream>>>(G, X, W200);
    {
      dim3 grid((NFRAMES + 4 * FPW - 1) / (4 * FPW), rows);
      stft256_kernel<<<grid, 256, 0, stream>>>((const float*)X, P, part, W512, hann);
    }
    edrB_kernel<<<dim3(c, NG), 192, 0, stream>>>(P, part, accum, c);
  }
  final_kernel<<<1, 1, 0, stream>>>(accum, out);
}